// Round 13
// baseline (541.242 us; speedup 1.0000x reference)
//
#include <hip/hip_runtime.h>
#include <hip/hip_bf16.h>
#include <math.h>

typedef __attribute__((ext_vector_type(8))) short short8;      // 8 bf16 (4 VGPRs)
typedef __attribute__((ext_vector_type(4))) float f32x4;       // MFMA acc
typedef __attribute__((ext_vector_type(4))) unsigned short us4;

#define MFMA16(a,b,c) __builtin_amdgcn_mfma_f32_16x16x32_bf16((a),(b),(c),0,0,0)

// ---------------- workspace layout (bytes) ----------------
// W1cat: bf16 fragment-ordered [9][ks=8][nt=8][lane=64][j=8]
// W2cat: bf16 fragment-ordered [7][ks=4][nt=8][lane=64][j=8]
#define OFF_W1CAT   0u
#define OFF_W2CAT   589824u
#define OFF_B1      950272u    // f32 [9][128]
#define OFF_B2      954880u    // f32 [7][128]
#define OFF_LNG     958464u    // f32 [3][128] (D0,D1,S gains)
#define OFF_LNB     960000u    // f32 [3][128]
#define OFF_BSC     961536u    // f32 [2][128] B_g
#define OFF_BBI     962560u    // f32 [2][128] B_be
#define OFF_USAGE   963584u    // f32 [8]
#define OFF_W8      963712u    // f32 [32768][8]
#define OFF_W1T     2012288u   // f32 [257][128]  gate W1 transposed
#define OFF_GW1HF   2143872u   // bf16 frag [8][8][64][8] gate W1 hi
#define OFF_GW1LF   2209408u   // bf16 frag gate W1 lo

#define DELTA 2e-3f

__device__ __forceinline__ unsigned short f2bf(float f) {
  union { float f; unsigned u; } v; v.f = f;
  return (unsigned short)((v.u + 0x7fffu + ((v.u >> 16) & 1u)) >> 16);
}
__device__ __forceinline__ float bf2f(unsigned short b) {
  union { unsigned u; float f; } v; v.u = ((unsigned)b) << 16; return v.f;
}
// ---- fast activations ----
__device__ __forceinline__ float frcp(float x) { return __builtin_amdgcn_rcpf(x); }
__device__ __forceinline__ float ftanh(float x) {          // moe epilogue (loose tol)
  float ax = fabsf(x);
  float t = __expf(-2.f * ax);
  float r = (1.f - t) * frcp(1.f + t);
  return copysignf(r, x);
}
__device__ __forceinline__ float ftanh_acc(float x) {      // gate fast path (IEEE div)
  float ax = fabsf(x);
  float t = __expf(-2.f * ax);
  float r = (1.f - t) / (1.f + t);
  return copysignf(r, x);
}
__device__ __forceinline__ float fsilu(float x) {
  return x * frcp(1.f + __expf(-x));
}
__device__ __forceinline__ float fgelu(float x) {   // exact-erf form, A&S 7.1.26
  float ax = fabsf(x) * 0.70710678118654752f;
  float t = frcp(fmaf(0.3275911f, ax, 1.f));
  float p = fmaf(t, 1.061405429f, -1.453152027f);
  p = fmaf(t, p, 1.421413741f);
  p = fmaf(t, p, -0.284496736f);
  p = fmaf(t, p, 0.254829592f);
  p *= t;
  float erfv = copysignf(fmaf(-p, __expf(-ax * ax), 1.f), x);
  return 0.5f * x * (1.f + erfv);
}

// ============== prep: pack weights (fragment-ordered), fold conv ==============
__global__ __launch_bounds__(256) void prep_kernel(
    const float* __restrict__ A_W1, const float* __restrict__ A_b1,
    const float* __restrict__ A_W2, const float* __restrict__ A_b2,
    const float* __restrict__ B_W1, const float* __restrict__ B_b1,
    const float* __restrict__ B_g,  const float* __restrict__ B_be,
    const float* __restrict__ B_W2, const float* __restrict__ B_b2,
    const float* __restrict__ C_cw, const float* __restrict__ C_cb,
    const float* __restrict__ C_W,  const float* __restrict__ C_b,
    const float* __restrict__ D_W1, const float* __restrict__ D_b1,
    const float* __restrict__ D_g,  const float* __restrict__ D_be,
    const float* __restrict__ D_W2, const float* __restrict__ D_b2,
    const float* __restrict__ S_W1, const float* __restrict__ S_b1,
    const float* __restrict__ S_g,  const float* __restrict__ S_be,
    const float* __restrict__ S_W2, const float* __restrict__ S_b2,
    const float* __restrict__ G_W1,
    unsigned short* __restrict__ W1cat, unsigned short* __restrict__ W2cat,
    float* __restrict__ W1T,
    unsigned short* __restrict__ GW1HF, unsigned short* __restrict__ GW1LF,
    float* __restrict__ b1cat, float* __restrict__ b2cat,
    float* __restrict__ lng, float* __restrict__ lnb,
    float* __restrict__ bsc, float* __restrict__ bbi,
    float* __restrict__ usage)
{
  int tid = blockIdx.x * 256 + threadIdx.x;
  if (tid < 294912) {                       // W1cat, fragment order
    int g = tid >> 15, rem = tid & 32767;
    int j = rem & 7, lane = (rem >> 3) & 63, nt = (rem >> 9) & 7, ks = rem >> 12;
    int p = nt * 16 + (lane & 15);
    int k = ks * 32 + (lane >> 4) * 8 + j;
    int src = p * 256 + k;
    float v;
    if (g < 2)      v = A_W1[g * 32768 + src];
    else if (g < 4) v = B_W1[(g - 2) * 32768 + src];
    else if (g < 6) {                       // Weff = conv folded into C_W
      int e = g - 4;
      v = 0.f;
      for (int c = 0; c < 4; ++c)
        for (int jj = 0; jj < 3; ++jj) {
          int h = k + 1 - jj;
          if (h >= 0 && h < 256)
            v += C_cw[e*12 + c*3 + jj] * C_W[e*131072 + p*1024 + c*256 + h];
        }
    }
    else if (g < 8) v = D_W1[(g - 6) * 32768 + src];
    else            v = S_W1[src];
    W1cat[tid] = f2bf(v);
    return;
  }
  tid -= 294912;
  if (tid < 114688) {                       // W2cat, fragment order
    int g = tid >> 14, rem = tid & 16383;
    int j = rem & 7, lane = (rem >> 3) & 63, nt = (rem >> 9) & 7, ks = rem >> 12;
    int p = nt * 16 + (lane & 15);
    int k = ks * 32 + (lane >> 4) * 8 + j;
    int src = p * 128 + k;
    float v;
    if (g < 2)      v = A_W2[g * 16384 + src];
    else if (g < 4) v = B_W2[(g - 2) * 16384 + src];
    else if (g < 6) v = D_W2[(g - 4) * 16384 + src];
    else            v = S_W2[src];
    W2cat[tid] = f2bf(v);
    return;
  }
  tid -= 114688;
  if (tid < 32896) {                        // W1T[k][o] = G_W1[o][k]
    int k = tid / 128, o = tid % 128;
    W1T[tid] = G_W1[o * 257 + k];
    return;
  }
  tid -= 32896;
  if (tid < 32768) {                        // gate W1 hi/lo, fragment order
    int j = tid & 7, lane = (tid >> 3) & 63, nt = (tid >> 9) & 7, ks = tid >> 12;
    int o = nt * 16 + (lane & 15);
    int k = ks * 32 + (lane >> 4) * 8 + j;
    float v = G_W1[o * 257 + k];
    unsigned short h = f2bf(v);
    GW1HF[tid] = h;
    GW1LF[tid] = f2bf(v - bf2f(h));
    return;
  }
  tid -= 32768;
  if (tid < 1152) {                         // b1cat (C fold added by prep2)
    int g = tid / 128, p = tid % 128;
    float v;
    if (g < 2)      v = A_b1[tid];
    else if (g < 4) v = B_b1[p + (g - 2) * 128];
    else if (g < 6) v = C_b[(g - 4) * 128 + p];
    else if (g < 8) v = D_b1[p + (g - 6) * 128];
    else            v = S_b1[p];
    b1cat[tid] = v;
    return;
  }
  tid -= 1152;
  if (tid < 896) {                          // b2cat
    int g = tid / 128, p = tid % 128;
    float v;
    if (g < 2)      v = A_b2[tid];
    else if (g < 4) v = B_b2[p + (g - 2) * 128];
    else if (g < 6) v = D_b2[p + (g - 4) * 128];
    else            v = S_b2[p];
    b2cat[tid] = v;
    return;
  }
  tid -= 896;
  if (tid < 768) {                          // LN gains/biases (D0,D1,S)
    if (tid < 384) {
      int j = tid / 128, p = tid % 128;
      lng[tid] = (j < 2) ? D_g[tid] : S_g[p];
    } else {
      int q = tid - 384; int j = q / 128, p = q % 128;
      lnb[q] = (j < 2) ? D_be[q] : S_be[p];
    }
    return;
  }
  tid -= 768;
  if (tid < 512) {                          // B scale/shift
    if (tid < 256) bsc[tid] = B_g[tid];
    else           bbi[tid - 256] = B_be[tid - 256];
    return;
  }
  tid -= 512;
  if (tid < 8) usage[tid] = 0.f;
}

// prep2: parallel conv-bias fold
__global__ __launch_bounds__(256) void prep2_kernel(
    const float* __restrict__ C_cw_unused, const float* __restrict__ C_cb,
    const float* __restrict__ C_W, float* __restrict__ b1cat)
{
  int tid = blockIdx.x * 256 + threadIdx.x;   // 1024 threads: (e,p,c)
  int e = tid >> 9, rem = tid & 511;
  int p = rem >> 2, c = rem & 3;
  const float4* row = (const float4*)(C_W + e*131072 + p*1024 + c*256);
  float s = 0.f;
  for (int q = 0; q < 64; ++q) {
    float4 v = row[q];
    s += v.x + v.y + v.z + v.w;
  }
  atomicAdd(&b1cat[(4 + e) * 128 + p], C_cb[e * 4 + c] * s);
}

// ============== gate v4: bf16x3 MFMA fast pass + inline np-exact slow path ==============
// grid 256 x 512thr. Wave = 16 tokens. Fast logits via MFMA (err ~3e-5); tokens
// with rank-4/5 gap < DELTA recompute via the round-4/12 bit-exact np emulation.
__global__ __launch_bounds__(512, 2) void gate_kernel(
    const float* __restrict__ x, const int* __restrict__ modality,
    const unsigned short* __restrict__ GW1HF, const unsigned short* __restrict__ GW1LF,
    const float* __restrict__ W1T, const float* __restrict__ G_W1,
    const float* __restrict__ G_b1, const float* __restrict__ G_W2,
    const float* __restrict__ G_b2,
    float* __restrict__ w8full, float* __restrict__ usage)
{
  __shared__ unsigned char smem[147520];
  short8* BhL   = (short8*)smem;                  // 64KB
  short8* BlL   = (short8*)(smem + 65536);        // 64KB
  float*  ws2   = (float*)(smem + 131072);        // [8][128] f32
  float*  ghsl  = (float*)(smem + 135168);        // [8 waves][128] f32
  float*  xsl   = (float*)(smem + 139264);        // [8 waves][256] f32
  unsigned* flagw = (unsigned*)(smem + 147456);   // [8]

  const int tid = threadIdx.x;
  const int wv = tid >> 6, lane = tid & 63;
  const int l15 = lane & 15, l4 = lane >> 4;
  const int tbw = blockIdx.x * 128 + wv * 16;

  const short8* srcH = (const short8*)GW1HF;
  const short8* srcL = (const short8*)GW1LF;
#pragma unroll
  for (int i = 0; i < 8; ++i) BhL[tid + i * 512] = srcH[tid + i * 512];
#pragma unroll
  for (int i = 0; i < 8; ++i) BlL[tid + i * 512] = srcL[tid + i * 512];
  for (int i = tid; i < 1024; i += 512) ws2[i] = G_W2[i];
  if (lane == 0) flagw[wv] = 0;

  // A-fragments hi/lo for the wave's 16 tokens
  short8 XH[8], XL[8];
#pragma unroll
  for (int ks = 0; ks < 8; ++ks) {
    const float* xr = x + (size_t)(tbw + l15) * 256 + ks * 32 + l4 * 8;
    float4 u = *(const float4*)xr, v = *(const float4*)(xr + 4);
    float xv[8] = {u.x, u.y, u.z, u.w, v.x, v.y, v.z, v.w};
    short8 hh, ll;
#pragma unroll
    for (int j2 = 0; j2 < 8; ++j2) {
      unsigned short h = f2bf(xv[j2]);
      hh[j2] = (short)h;
      ll[j2] = (short)f2bf(xv[j2] - bf2f(h));
    }
    XH[ks] = hh; XL[ks] = ll;
  }
  __syncthreads();

  f32x4 zero = {0.f, 0.f, 0.f, 0.f};
  f32x4 acc[8];
#pragma unroll
  for (int nt = 0; nt < 8; ++nt) acc[nt] = zero;
#pragma unroll
  for (int ks = 0; ks < 8; ++ks) {
#pragma unroll
    for (int nt = 0; nt < 8; ++nt) {
      short8 bh = BhL[(ks * 8 + nt) * 64 + lane];
      short8 bl = BlL[(ks * 8 + nt) * 64 + lane];
      acc[nt] = MFMA16(XH[ks], bh, acc[nt]);
      acc[nt] = MFMA16(XH[ks], bl, acc[nt]);
      acc[nt] = MFMA16(XL[ks], bh, acc[nt]);
    }
  }
  // modality column + bias + tanh
  float mf[4];
#pragma unroll
  for (int r = 0; r < 4; ++r) mf[r] = (float)modality[tbw + l4 * 4 + r];
  float ghreg[8][4];
#pragma unroll
  for (int nt = 0; nt < 8; ++nt) {
    int o = nt * 16 + l15;
    float wm = G_W1[o * 257 + 256];
    float b = G_b1[o];
#pragma unroll
    for (int r = 0; r < 4; ++r)
      ghreg[nt][r] = ftanh_acc(fmaf(mf[r], wm, acc[nt][r]) + b);
  }
  // layer 2: per-lane partials + 16-lane-group xor reduce
  float part[8][4];
#pragma unroll
  for (int e = 0; e < 8; ++e) {
    float w[8];
#pragma unroll
    for (int nt = 0; nt < 8; ++nt) w[nt] = ws2[e * 128 + nt * 16 + l15];
#pragma unroll
    for (int r = 0; r < 4; ++r) {
      float s = 0.f;
#pragma unroll
      for (int nt = 0; nt < 8; ++nt) s = fmaf(ghreg[nt][r], w[nt], s);
      part[e][r] = s;
    }
  }
#pragma unroll
  for (int m = 1; m <= 8; m <<= 1)
#pragma unroll
    for (int e = 0; e < 8; ++e)
#pragma unroll
      for (int r = 0; r < 4; ++r)
        part[e][r] += __shfl_xor(part[e][r], m);

  float uw[8];
#pragma unroll
  for (int e = 0; e < 8; ++e) uw[e] = 0.f;
  if (l15 == 0) {
    for (int r = 0; r < 4; ++r) {
      int token = tbw + l4 * 4 + r;
      float v[8];
#pragma unroll
      for (int e = 0; e < 8; ++e)
        v[e] = fminf(fmaxf((part[e][r] + G_b2[e]) / 0.7f, -10.f), 10.f);
      float tv[5]; int ti[5]; unsigned msk = 0;
      for (int kk = 0; kk < 5; ++kk) {
        float best = -1e30f; int bi = 0;
        for (int e = 0; e < 8; ++e)
          if (!((msk >> e) & 1u) && v[e] > best) { best = v[e]; bi = e; }
        tv[kk] = best; ti[kk] = bi; msk |= 1u << bi;
      }
      if (tv[3] - tv[4] < DELTA) {
        atomicOr(&flagw[wv], 1u << (l4 * 4 + r));
      } else {
        float mx = tv[0], den = 0.f, wk4[4];
#pragma unroll
        for (int kk = 0; kk < 4; ++kk) { wk4[kk] = expf(tv[kk] - mx); den += wk4[kk]; }
#pragma unroll
        for (int e = 0; e < 8; ++e) {
          float val = 0.f;
#pragma unroll
          for (int kk = 0; kk < 4; ++kk) if (ti[kk] == e) val = wk4[kk] / den;
          w8full[(size_t)token * 8 + e] = val;
        }
        float dall = 0.f, pe[8];
#pragma unroll
        for (int e = 0; e < 8; ++e) { pe[e] = expf(v[e] - mx); dall += pe[e]; }
#pragma unroll
        for (int e = 0; e < 8; ++e) uw[e] += pe[e] / dall;
      }
    }
  }
#pragma unroll
  for (int m = 16; m <= 32; m <<= 1)
#pragma unroll
    for (int e = 0; e < 8; ++e) uw[e] += __shfl_xor(uw[e], m);
  if (lane == 0)
    for (int e = 0; e < 8; ++e) atomicAdd(usage + e, uw[e]);

  // ---- slow path: np-exact recompute for flagged tokens (usually none) ----
  unsigned fl = flagw[wv];                  // same-wave LDS: ordered, no barrier
  while (fl) {
    int t = __builtin_ctz(fl); fl &= fl - 1;
    int T = tbw + t;
#pragma unroll
    for (int q = 0; q < 4; ++q)
      xsl[wv * 256 + q * 64 + lane] = x[(size_t)T * 256 + q * 64 + lane];
    float a0 = 0.f, a1 = 0.f;
    for (int k = 0; k < 256; ++k) {         // exact sequential-k chain (np order)
      float xv = xsl[wv * 256 + k];
      a0 = fmaf(xv, W1T[k * 128 + lane], a0);
      a1 = fmaf(xv, W1T[k * 128 + 64 + lane], a1);
    }
    {
      float xv = (float)modality[T];
      a0 = fmaf(xv, W1T[256 * 128 + lane], a0);
      a1 = fmaf(xv, W1T[256 * 128 + 64 + lane], a1);
    }
    ghsl[wv * 128 + lane]      = (float)tanh((double)(a0 + G_b1[lane]));
    ghsl[wv * 128 + 64 + lane] = (float)tanh((double)(a1 + G_b1[64 + lane]));
    float lg = 0.f;
    if (lane < 8)
      for (int o = 0; o < 128; ++o)         // exact sequential-o chain
        lg = fmaf(ghsl[wv * 128 + o], ws2[lane * 128 + o], lg);
    float v[8];
#pragma unroll
    for (int e = 0; e < 8; ++e) v[e] = __shfl(lg, e);
    if (lane == 0) {
#pragma unroll
      for (int e = 0; e < 8; ++e)
        v[e] = fminf(fmaxf((v[e] + G_b2[e]) / 0.7f, -10.f), 10.f);
      float tv[4]; int ti[4]; unsigned msk = 0;
      for (int kk = 0; kk < 4; ++kk) {
        float best = -1e30f; int bi = 0;
        for (int e = 0; e < 8; ++e)
          if (!((msk >> e) & 1u) && v[e] > best) { best = v[e]; bi = e; }
        tv[kk] = best; ti[kk] = bi; msk |= 1u << bi;
      }
      float mx = tv[0], den = 0.f, wk4[4];
#pragma unroll
      for (int kk = 0; kk < 4; ++kk) { wk4[kk] = expf(tv[kk] - mx); den += wk4[kk]; }
#pragma unroll
      for (int e = 0; e < 8; ++e) {
        float val = 0.f;
#pragma unroll
        for (int kk = 0; kk < 4; ++kk) if (ti[kk] == e) val = wk4[kk] / den;
        w8full[(size_t)T * 8 + e] = val;
      }
      float dall = 0.f, pe[8];
#pragma unroll
      for (int e = 0; e < 8; ++e) { pe[e] = expf(v[e] - mx); dall += pe[e]; }
      for (int e = 0; e < 8; ++e) atomicAdd(usage + e, pe[e] / dall);
    }
  }
}

// ============== moe v10: token-block/block, fam loop, LDS weights, reg combine ==============
__global__ __launch_bounds__(512, 2) void moe_kernel(
    const float* __restrict__ x,
    const unsigned short* __restrict__ W1cat, const unsigned short* __restrict__ W2cat,
    const float* __restrict__ b1cat, const float* __restrict__ b2cat,
    const float* __restrict__ lng, const float* __restrict__ lnb,
    const float* __restrict__ bsc, const float* __restrict__ bbi,
    const float* __restrict__ w8full, float* __restrict__ out)
{
  __shared__ unsigned char smem[131072];    // W1L 64K | W2L 32K | HS 8x4K
  short8* W1L = (short8*)smem;              // 4096 frags
  short8* W2L = (short8*)(smem + 65536);    // 2048 frags
  unsigned char* HS = smem + 98304 + (threadIdx.x >> 6) * 4096;

  const int tid = threadIdx.x;
  const int wv = tid >> 6, lane = tid & 63;
  const int l15 = lane & 15, l4 = lane >> 4;
  const int tb = blockIdx.x * 128 + wv * 16;
  const short8* W1f = (const short8*)W1cat;
  const short8* W2f = (const short8*)W2cat;

  short8 A[8];
#pragma unroll
  for (int ks = 0; ks < 8; ++ks) {
    const float* xr = x + (size_t)(tb + l15) * 256 + ks * 32 + l4 * 8;
    float4 u = *(const float4*)xr, v = *(const float4*)(xr + 4);
    short8 a;
    a[0]=(short)f2bf(u.x); a[1]=(short)f2bf(u.y); a[2]=(short)f2bf(u.z); a[3]=(short)f2bf(u.w);
    a[4]=(short)f2bf(v.x); a[5]=(short)f2bf(v.y); a[6]=(short)f2bf(v.z); a[7]=(short)f2bf(v.w);
    A[ks] = a;
  }

  f32x4 zero = {0.f, 0.f, 0.f, 0.f};
  f32x4 pacc[8];
#pragma unroll
  for (int nt = 0; nt < 8; ++nt) pacc[nt] = zero;
  const float RS = 1.0f / sqrtf(1.0f + 1e-5f);

  short8 stg[12];
#pragma unroll
  for (int i = 0; i < 8; ++i) stg[i] = W1f[tid + i * 512];
#pragma unroll
  for (int i = 0; i < 4; ++i) stg[8 + i] = W2f[tid + i * 512];

  for (int g = 0; g < 9; ++g) {
    const int type = (g < 2) ? 0 : (g < 4) ? 1 : (g < 6) ? 2 : (g < 8) ? 3 : 4;
    const int g2 = (g < 4) ? g : ((g == 8) ? 6 : g - 2);

    __syncthreads();
#pragma unroll
    for (int i = 0; i < 8; ++i) W1L[tid + i * 512] = stg[i];
#pragma unroll
    for (int i = 0; i < 4; ++i) W2L[tid + i * 512] = stg[8 + i];
    if (g < 8) {
      int gn = g + 1;
      int g2n = (gn < 4) ? gn : ((gn == 8) ? 6 : gn - 2);
#pragma unroll
      for (int i = 0; i < 8; ++i) stg[i] = W1f[(size_t)gn * 4096 + tid + i * 512];
#pragma unroll
      for (int i = 0; i < 4; ++i) stg[8 + i] = W2f[(size_t)g2n * 2048 + tid + i * 512];
    }
    __syncthreads();

    f32x4 acc[8];
#pragma unroll
    for (int nt = 0; nt < 8; ++nt) acc[nt] = zero;
#pragma unroll
    for (int ks = 0; ks < 8; ++ks)
#pragma unroll
      for (int nt = 0; nt < 8; ++nt)
        acc[nt] = MFMA16(A[ks], W1L[(ks * 8 + nt) * 64 + lane], acc[nt]);

    const float* b1 = b1cat + g * 128;

    if (type == 2) {
#pragma unroll
      for (int r = 0; r < 4; ++r) {
        float wv_ = w8full[(size_t)(tb + l4 * 4 + r) * 8 + g];
#pragma unroll
        for (int nt = 0; nt < 8; ++nt) {
          float h = fgelu(acc[nt][r] + b1[nt * 16 + l15]);
          pacc[nt][r] += wv_ * h;
        }
      }
      continue;
    }
#pragma unroll
    for (int r = 0; r < 4; ++r)
#pragma unroll
      for (int nt = 0; nt < 8; ++nt) {
        float h = acc[nt][r] + b1[nt * 16 + l15];
        if (type == 0)      h = fmaxf(h, 0.f);
        else if (type == 1) {
          int col = (g - 2) * 128 + nt * 16 + l15;
          h = ftanh(h) * RS * bsc[col] + bbi[col];
        }
        else if (type == 3) h = fsilu(h);
        else                h = fmaxf(h, 0.f);
        acc[nt][r] = h;
      }
    if (type >= 3) {
      int li = (type == 4) ? 2 : (g - 6);
#pragma unroll
      for (int r = 0; r < 4; ++r) {
        float s1 = 0.f, s2 = 0.f;
#pragma unroll
        for (int nt = 0; nt < 8; ++nt) { float h = acc[nt][r]; s1 += h; s2 += h * h; }
        for (int m = 1; m <= 8; m <<= 1) { s1 += __shfl_xor(s1, m); s2 += __shfl_xor(s2, m); }
        float mu = s1 * (1.f / 128.f);
        float var = s2 * (1.f / 128.f) - mu * mu;
        float sc = __builtin_amdgcn_rsqf(var + 1e-5f);
#pragma unroll
        for (int nt = 0; nt < 8; ++nt) {
          int col = nt * 16 + l15;
          acc[nt][r] = (acc[nt][r] - mu) * sc * lng[li * 128 + col] + lnb[li * 128 + col];
        }
      }
    }
#pragma unroll
    for (int r = 0; r < 4; ++r) {
      int row = l4 * 4 + r;
#pragma unroll
      for (int nt = 0; nt < 8; ++nt) {
        int bytecol = (nt * 16 + l15) * 2;
        int addr = row * 256 + ((((bytecol >> 4) ^ (row & 7)) << 4) | (bytecol & 15));
        *(unsigned short*)(HS + addr) = f2bf(acc[nt][r]);
      }
    }
    short8 a2[4];
#pragma unroll
    for (int ks = 0; ks < 4; ++ks) {
      int ar = l15 * 256 + ((((ks * 4 + l4) ^ (l15 & 7)) << 4));
      a2[ks] = *(const short8*)(HS + ar);
    }
    f32x4 acc2[8];
#pragma unroll
    for (int nt = 0; nt < 8; ++nt) acc2[nt] = zero;
#pragma unroll
    for (int ks = 0; ks < 4; ++ks)
#pragma unroll
      for (int nt = 0; nt < 8; ++nt)
        acc2[nt] = MFMA16(a2[ks], W2L[(ks * 8 + nt) * 64 + lane], acc2[nt]);

    const float* b2 = b2cat + g2 * 128;
    if (type == 4) {
#pragma unroll
      for (int r = 0; r < 4; ++r) {
        int token = tb + l4 * 4 + r;
#pragma unroll
        for (int nt = 0; nt < 8; ++nt)
          out[(size_t)token * 128 + nt * 16 + l15] = acc2[nt][r] + b2[nt * 16 + l15];
      }
    } else {
#pragma unroll
      for (int r = 0; r < 4; ++r) {
        float wv_ = w8full[(size_t)(tb + l4 * 4 + r) * 8 + g];
#pragma unroll
        for (int nt = 0; nt < 8; ++nt)
          pacc[nt][r] += wv_ * (acc2[nt][r] + b2[nt * 16 + l15]);
      }
    }
  }
#pragma unroll
  for (int r = 0; r < 4; ++r) {
    int token = tb + l4 * 4 + r;
#pragma unroll
    for (int nt = 0; nt < 8; ++nt)
      out[4194304 + (size_t)token * 128 + nt * 16 + l15] = pacc[nt][r];
  }
}

// ============== aux scalar ==============
__global__ void aux_kernel(const float* __restrict__ usage, float* __restrict__ out) {
  if (threadIdx.x == 0 && blockIdx.x == 0) {
    float a = 0.f;
    for (int e = 0; e < 8; ++e) {
      float u = usage[e] * (1.0f / 32768.0f);
      a += 0.125f * (logf(0.125f) - logf(u + 1e-10f));
    }
    out[8388608] = a * 0.125f;
  }
}

extern "C" void kernel_launch(void* const* d_in, const int* in_sizes, int n_in,
                              void* d_out, int out_size, void* d_ws, size_t ws_size,
                              hipStream_t stream) {
  (void)in_sizes; (void)n_in; (void)out_size; (void)ws_size;
  const float* x    = (const float*)d_in[0];
  const int*   mod  = (const int*)d_in[1];
  const float* A_W1 = (const float*)d_in[2];
  const float* A_b1 = (const float*)d_in[3];
  const float* A_W2 = (const float*)d_in[4];
  const float* A_b2 = (const float*)d_in[5];
  const float* B_W1 = (const float*)d_in[6];
  const float* B_b1 = (const float*)d_in[7];
  const float* B_g  = (const float*)d_in[8];
  const float* B_be = (const float*)d_in[9];
  const float* B_W2 = (const float*)d_in[10];
  const float* B_b2 = (const float*)d_in[11];
  const float* C_cw = (const float*)d_in[12];
  const float* C_cb = (const float*)d_in[13];
  const float* C_W  = (const float*)d_in[14];
  const float* C_b  = (const float*)d_in[15];
  const float* D_W1 = (const float*)d_in[16];
  const float* D_b1 = (const float*)d_in[17];
  const float* D_g  = (const float*)d_in[18];
  const float* D_be = (const float*)d_in[19];
  const float* D_W2 = (const float*)d_in[20];
  const float* D_b2 = (const float*)d_in[21];
  const float* S_W1 = (const float*)d_in[22];
  const float* S_b1 = (const float*)d_in[23];
  const float* S_g  = (const float*)d_in[24];
  const float* S_be = (const float*)d_in[25];
  const float* S_W2 = (const float*)d_in[26];
  const float* S_b2 = (const float*)d_in[27];
  const float* G_W1 = (const float*)d_in[28];
  const float* G_b1 = (const float*)d_in[29];
  const float* G_W2 = (const float*)d_in[30];
  const float* G_b2 = (const float*)d_in[31];

  char* ws = (char*)d_ws;
  unsigned short* W1cat = (unsigned short*)(ws + OFF_W1CAT);
  unsigned short* W2cat = (unsigned short*)(ws + OFF_W2CAT);
  float* W1T    = (float*)(ws + OFF_W1T);
  unsigned short* GW1HF = (unsigned short*)(ws + OFF_GW1HF);
  unsigned short* GW1LF = (unsigned short*)(ws + OFF_GW1LF);
  float* b1cat  = (float*)(ws + OFF_B1);
  float* b2cat  = (float*)(ws + OFF_B2);
  float* lng    = (float*)(ws + OFF_LNG);
  float* lnb    = (float*)(ws + OFF_LNB);
  float* bsc    = (float*)(ws + OFF_BSC);
  float* bbi    = (float*)(ws + OFF_BBI);
  float* usage  = (float*)(ws + OFF_USAGE);
  float* w8full = (float*)(ws + OFF_W8);
  float* out    = (float*)d_out;

  prep_kernel<<<1870, 256, 0, stream>>>(A_W1, A_b1, A_W2, A_b2, B_W1, B_b1, B_g, B_be,
      B_W2, B_b2, C_cw, C_cb, C_W, C_b, D_W1, D_b1, D_g, D_be, D_W2, D_b2,
      S_W1, S_b1, S_g, S_be, S_W2, S_b2, G_W1,
      W1cat, W2cat, W1T, GW1HF, GW1LF, b1cat, b2cat, lng, lnb, bsc, bbi, usage);
  prep2_kernel<<<4, 256, 0, stream>>>(C_cw, C_cb, C_W, b1cat);
  gate_kernel<<<256, 512, 0, stream>>>(x, mod, GW1HF, GW1LF, W1T, G_W1,
      G_b1, G_W2, G_b2, w8full, usage);
  moe_kernel<<<256, 512, 0, stream>>>(x, W1cat, W2cat, b1cat, b2cat, lng, lnb,
      bsc, bbi, w8full, out);
  aux_kernel<<<1, 64, 0, stream>>>(usage, out);
}

// Round 14
// 408.504 us; speedup vs baseline: 1.3249x; 1.3249x over previous
//
#include <hip/hip_runtime.h>
#include <hip/hip_bf16.h>
#include <math.h>

typedef __attribute__((ext_vector_type(8))) short short8;      // 8 bf16 (4 VGPRs)
typedef __attribute__((ext_vector_type(4))) float f32x4;       // MFMA acc
typedef __attribute__((ext_vector_type(4))) unsigned short us4;

#define MFMA16(a,b,c) __builtin_amdgcn_mfma_f32_16x16x32_bf16((a),(b),(c),0,0,0)

// ---------------- workspace layout (bytes) ----------------
#define OFF_W1CAT   0u         // bf16 frag [9][8][8][64][8]
#define OFF_W2CAT   589824u    // bf16 frag [7][4][8][64][8]
#define OFF_B1      950272u    // f32 [9][128]
#define OFF_B2      954880u    // f32 [7][128]
#define OFF_LNG     958464u    // f32 [3][128]
#define OFF_LNB     960000u    // f32 [3][128]
#define OFF_BSC     961536u    // f32 [2][128]
#define OFF_BBI     962560u    // f32 [2][128]
#define OFF_USAGE   963584u    // f32 [8]
#define OFF_W8      963712u    // f32 [32768][8]
#define OFF_W1T     2012288u   // f32 [257][128]
#define OFF_GW1HF   2143872u   // bf16 frag [8][8][64][8]
#define OFF_GW1LF   2209408u
#define OFF_CNT     2274944u   // int
#define OFF_LIST    2275008u   // int [32768]

#define DELTA 2e-3f

__device__ __forceinline__ unsigned short f2bf(float f) {
  union { float f; unsigned u; } v; v.f = f;
  return (unsigned short)((v.u + 0x7fffu + ((v.u >> 16) & 1u)) >> 16);
}
__device__ __forceinline__ float bf2f(unsigned short b) {
  union { unsigned u; float f; } v; v.u = ((unsigned)b) << 16; return v.f;
}
__device__ __forceinline__ float frcp(float x) { return __builtin_amdgcn_rcpf(x); }
__device__ __forceinline__ float ftanh(float x) {          // moe epilogue
  float ax = fabsf(x);
  float t = __expf(-2.f * ax);
  float r = (1.f - t) * frcp(1.f + t);
  return copysignf(r, x);
}
__device__ __forceinline__ float ftanh_acc(float x) {      // gate fast path
  float ax = fabsf(x);
  float t = __expf(-2.f * ax);
  float r = (1.f - t) / (1.f + t);
  return copysignf(r, x);
}
__device__ __forceinline__ float fsilu(float x) {
  return x * frcp(1.f + __expf(-x));
}
__device__ __forceinline__ float fgelu(float x) {
  float ax = fabsf(x) * 0.70710678118654752f;
  float t = frcp(fmaf(0.3275911f, ax, 1.f));
  float p = fmaf(t, 1.061405429f, -1.453152027f);
  p = fmaf(t, p, 1.421413741f);
  p = fmaf(t, p, -0.284496736f);
  p = fmaf(t, p, 0.254829592f);
  p *= t;
  float erfv = copysignf(fmaf(-p, __expf(-ax * ax), 1.f), x);
  return 0.5f * x * (1.f + erfv);
}

// ============== prep ==============
__global__ __launch_bounds__(256) void prep_kernel(
    const float* __restrict__ A_W1, const float* __restrict__ A_b1,
    const float* __restrict__ A_W2, const float* __restrict__ A_b2,
    const float* __restrict__ B_W1, const float* __restrict__ B_b1,
    const float* __restrict__ B_g,  const float* __restrict__ B_be,
    const float* __restrict__ B_W2, const float* __restrict__ B_b2,
    const float* __restrict__ C_cw, const float* __restrict__ C_cb,
    const float* __restrict__ C_W,  const float* __restrict__ C_b,
    const float* __restrict__ D_W1, const float* __restrict__ D_b1,
    const float* __restrict__ D_g,  const float* __restrict__ D_be,
    const float* __restrict__ D_W2, const float* __restrict__ D_b2,
    const float* __restrict__ S_W1, const float* __restrict__ S_b1,
    const float* __restrict__ S_g,  const float* __restrict__ S_be,
    const float* __restrict__ S_W2, const float* __restrict__ S_b2,
    const float* __restrict__ G_W1,
    unsigned short* __restrict__ W1cat, unsigned short* __restrict__ W2cat,
    float* __restrict__ W1T,
    unsigned short* __restrict__ GW1HF, unsigned short* __restrict__ GW1LF,
    float* __restrict__ b1cat, float* __restrict__ b2cat,
    float* __restrict__ lng, float* __restrict__ lnb,
    float* __restrict__ bsc, float* __restrict__ bbi,
    float* __restrict__ usage)
{
  int tid = blockIdx.x * 256 + threadIdx.x;
  if (tid < 294912) {                       // W1cat, fragment order
    int g = tid >> 15, rem = tid & 32767;
    int j = rem & 7, lane = (rem >> 3) & 63, nt = (rem >> 9) & 7, ks = rem >> 12;
    int p = nt * 16 + (lane & 15);
    int k = ks * 32 + (lane >> 4) * 8 + j;
    int src = p * 256 + k;
    float v;
    if (g < 2)      v = A_W1[g * 32768 + src];
    else if (g < 4) v = B_W1[(g - 2) * 32768 + src];
    else if (g < 6) {
      int e = g - 4;
      v = 0.f;
      for (int c = 0; c < 4; ++c)
        for (int jj = 0; jj < 3; ++jj) {
          int h = k + 1 - jj;
          if (h >= 0 && h < 256)
            v += C_cw[e*12 + c*3 + jj] * C_W[e*131072 + p*1024 + c*256 + h];
        }
    }
    else if (g < 8) v = D_W1[(g - 6) * 32768 + src];
    else            v = S_W1[src];
    W1cat[tid] = f2bf(v);
    return;
  }
  tid -= 294912;
  if (tid < 114688) {                       // W2cat, fragment order
    int g = tid >> 14, rem = tid & 16383;
    int j = rem & 7, lane = (rem >> 3) & 63, nt = (rem >> 9) & 7, ks = rem >> 12;
    int p = nt * 16 + (lane & 15);
    int k = ks * 32 + (lane >> 4) * 8 + j;
    int src = p * 128 + k;
    float v;
    if (g < 2)      v = A_W2[g * 16384 + src];
    else if (g < 4) v = B_W2[(g - 2) * 16384 + src];
    else if (g < 6) v = D_W2[(g - 4) * 16384 + src];
    else            v = S_W2[src];
    W2cat[tid] = f2bf(v);
    return;
  }
  tid -= 114688;
  if (tid < 32896) {                        // W1T[k][o] = G_W1[o][k]
    int k = tid / 128, o = tid % 128;
    W1T[tid] = G_W1[o * 257 + k];
    return;
  }
  tid -= 32896;
  if (tid < 32768) {                        // gate W1 hi/lo, fragment order
    int j = tid & 7, lane = (tid >> 3) & 63, nt = (tid >> 9) & 7, ks = tid >> 12;
    int o = nt * 16 + (lane & 15);
    int k = ks * 32 + (lane >> 4) * 8 + j;
    float v = G_W1[o * 257 + k];
    unsigned short h = f2bf(v);
    GW1HF[tid] = h;
    GW1LF[tid] = f2bf(v - bf2f(h));
    return;
  }
  tid -= 32768;
  if (tid < 1152) {                         // b1cat (C fold added by prep2)
    int g = tid / 128, p = tid % 128;
    float v;
    if (g < 2)      v = A_b1[tid];
    else if (g < 4) v = B_b1[p + (g - 2) * 128];
    else if (g < 6) v = C_b[(g - 4) * 128 + p];
    else if (g < 8) v = D_b1[p + (g - 6) * 128];
    else            v = S_b1[p];
    b1cat[tid] = v;
    return;
  }
  tid -= 1152;
  if (tid < 896) {                          // b2cat
    int g = tid / 128, p = tid % 128;
    float v;
    if (g < 2)      v = A_b2[tid];
    else if (g < 4) v = B_b2[p + (g - 2) * 128];
    else if (g < 6) v = D_b2[p + (g - 4) * 128];
    else            v = S_b2[p];
    b2cat[tid] = v;
    return;
  }
  tid -= 896;
  if (tid < 768) {
    if (tid < 384) {
      int j = tid / 128, p = tid % 128;
      lng[tid] = (j < 2) ? D_g[tid] : S_g[p];
    } else {
      int q = tid - 384; int j = q / 128, p = q % 128;
      lnb[q] = (j < 2) ? D_be[q] : S_be[p];
    }
    return;
  }
  tid -= 768;
  if (tid < 512) {
    if (tid < 256) bsc[tid] = B_g[tid];
    else           bbi[tid - 256] = B_be[tid - 256];
    return;
  }
  tid -= 512;
  if (tid < 8) usage[tid] = 0.f;
}

// prep2: conv-bias fold + counter zero
__global__ __launch_bounds__(256) void prep2_kernel(
    const float* __restrict__ C_cw_unused, const float* __restrict__ C_cb,
    const float* __restrict__ C_W, float* __restrict__ b1cat, int* __restrict__ cnt)
{
  int tid = blockIdx.x * 256 + threadIdx.x;
  if (tid == 0) *cnt = 0;
  int e = tid >> 9, rem = tid & 511;
  int p = rem >> 2, c = rem & 3;
  const float4* row = (const float4*)(C_W + e*131072 + p*1024 + c*256);
  float s = 0.f;
  for (int q = 0; q < 64; ++q) {
    float4 v = row[q];
    s += v.x + v.y + v.z + v.w;
  }
  atomicAdd(&b1cat[(4 + e) * 128 + p], C_cb[e * 4 + c] * s);
}

// ============== gate_fast: MFMA bf16x3, o-half split, flag compaction ==============
// 512 thr / 64 tokens per block, grid 512. Wave (tg,half): tokens tg*16..+16,
// outputs half*64..+64 (4 nt tiles). No weight staging (L2-resident frags).
__global__ __launch_bounds__(512, 4) void gate_fast_kernel(
    const float* __restrict__ x, const int* __restrict__ modality,
    const unsigned short* __restrict__ GW1HF, const unsigned short* __restrict__ GW1LF,
    const float* __restrict__ G_W1, const float* __restrict__ G_b1,
    const float* __restrict__ G_W2, const float* __restrict__ G_b2,
    float* __restrict__ w8full, float* __restrict__ usage,
    int* __restrict__ cnt, int* __restrict__ list)
{
  __shared__ float gh[64][132];
  __shared__ float lgs[64][9];
  const int tid = threadIdx.x;
  const int wv = tid >> 6, lane = tid & 63;
  const int l15 = lane & 15, l4 = lane >> 4;
  const int tg = wv >> 1, half = wv & 1;
  const int tb = blockIdx.x * 64;
  const int tw = tb + tg * 16;

  const short8* srcH = (const short8*)GW1HF;
  const short8* srcL = (const short8*)GW1LF;

  // A-fragments hi/lo for the wave's 16 tokens
  short8 XH[8], XL[8];
#pragma unroll
  for (int ks = 0; ks < 8; ++ks) {
    const float* xr = x + (size_t)(tw + l15) * 256 + ks * 32 + l4 * 8;
    float4 u = *(const float4*)xr, v = *(const float4*)(xr + 4);
    float xv[8] = {u.x, u.y, u.z, u.w, v.x, v.y, v.z, v.w};
    short8 hh, ll;
#pragma unroll
    for (int j2 = 0; j2 < 8; ++j2) {
      unsigned short h = f2bf(xv[j2]);
      hh[j2] = (short)h;
      ll[j2] = (short)f2bf(xv[j2] - bf2f(h));
    }
    XH[ks] = hh; XL[ks] = ll;
  }

  f32x4 zero = {0.f, 0.f, 0.f, 0.f};
  f32x4 acc[4];
#pragma unroll
  for (int n = 0; n < 4; ++n) acc[n] = zero;
#pragma unroll
  for (int ks = 0; ks < 8; ++ks) {
#pragma unroll
    for (int n = 0; n < 4; ++n) {
      int fi = ks * 512 + (half * 4 + n) * 64 + lane;
      short8 bh = srcH[fi];
      short8 bl = srcL[fi];
      acc[n] = MFMA16(XH[ks], bh, acc[n]);
      acc[n] = MFMA16(XH[ks], bl, acc[n]);
      acc[n] = MFMA16(XL[ks], bh, acc[n]);
    }
  }
  float mf[4];
#pragma unroll
  for (int r = 0; r < 4; ++r) mf[r] = (float)modality[tw + l4 * 4 + r];
#pragma unroll
  for (int n = 0; n < 4; ++n) {
    int o = (half * 4 + n) * 16 + l15;
    float wm = G_W1[o * 257 + 256];
    float b = G_b1[o];
#pragma unroll
    for (int r = 0; r < 4; ++r)
      gh[tg * 16 + l4 * 4 + r][o] = ftanh_acc(fmaf(mf[r], wm, acc[n][r]) + b);
  }
  __syncthreads();

  {                                         // layer 2: thread = (token, expert)
    int t2 = tid >> 3, e2 = tid & 7;
    float lg = 0.f;
    for (int o2 = 0; o2 < 128; ++o2)
      lg = fmaf(gh[t2][o2], G_W2[e2 * 128 + o2], lg);
    float s = (lg + G_b2[e2]) / 0.7f;
    lgs[t2][e2] = fminf(fmaxf(s, -10.f), 10.f);
  }
  __syncthreads();

  if (wv == 0) {                            // 64 tokens on 64 lanes
    int token = tb + lane;
    float v[8];
#pragma unroll
    for (int e = 0; e < 8; ++e) v[e] = lgs[lane][e];
    float tv[5]; int ti[5]; unsigned msk = 0;
    for (int kk = 0; kk < 5; ++kk) {
      float best = -1e30f; int bi = 0;
      for (int e = 0; e < 8; ++e)
        if (!((msk >> e) & 1u) && v[e] > best) { best = v[e]; bi = e; }
      tv[kk] = best; ti[kk] = bi; msk |= 1u << bi;
    }
    float uw[8];
#pragma unroll
    for (int e = 0; e < 8; ++e) uw[e] = 0.f;
    if (tv[3] - tv[4] < DELTA) {            // near-tie -> np-exact recompute later
      int idx = atomicAdd(cnt, 1);
      list[idx] = token;
    } else {
      float mx = tv[0], den = 0.f, wk4[4];
#pragma unroll
      for (int kk = 0; kk < 4; ++kk) { wk4[kk] = expf(tv[kk] - mx); den += wk4[kk]; }
#pragma unroll
      for (int e = 0; e < 8; ++e) {
        float val = 0.f;
#pragma unroll
        for (int kk = 0; kk < 4; ++kk) if (ti[kk] == e) val = wk4[kk] / den;
        w8full[(size_t)token * 8 + e] = val;
      }
      float dall = 0.f, pe[8];
#pragma unroll
      for (int e = 0; e < 8; ++e) { pe[e] = expf(v[e] - mx); dall += pe[e]; }
#pragma unroll
      for (int e = 0; e < 8; ++e) uw[e] = pe[e] / dall;
    }
    for (int m = 1; m <= 32; m <<= 1)
#pragma unroll
      for (int e = 0; e < 8; ++e) uw[e] += __shfl_xor(uw[e], m);
    if (lane == 0)
      for (int e = 0; e < 8; ++e) atomicAdd(usage + e, uw[e]);
  }
}

// ============== gate_slow: np-exact recompute of flagged tokens ==============
// wave = one token; lanes = 128 hidden outputs (2 chains). Bit-identical to the
// round-12 passing gate per (t,o): sequential-k fmaf, CR tanh, sequential-o L2.
__global__ __launch_bounds__(256, 8) void gate_slow_kernel(
    const float* __restrict__ x, const int* __restrict__ modality,
    const float* __restrict__ W1T, const float* __restrict__ G_b1,
    const float* __restrict__ G_W2, const float* __restrict__ G_b2,
    const int* __restrict__ cnt, const int* __restrict__ list,
    float* __restrict__ w8full, float* __restrict__ usage)
{
  __shared__ float gh[4][128];
  const int wvl = threadIdx.x >> 6, lane = threadIdx.x & 63;
  const int wid = blockIdx.x * 4 + wvl;
  const int n = *cnt;
  for (int i = wid; i < n; i += 1024) {
    const int T = __builtin_amdgcn_readfirstlane(list[i]);
    const float* xr = x + (size_t)T * 256;
    float a0 = 0.f, a1 = 0.f;
#pragma unroll 4
    for (int k = 0; k < 256; ++k) {         // exact sequential-k chain (np order)
      float xv = xr[k];
      a0 = fmaf(xv, W1T[k * 128 + lane], a0);
      a1 = fmaf(xv, W1T[k * 128 + 64 + lane], a1);
    }
    {
      float xm = (float)modality[T];
      a0 = fmaf(xm, W1T[256 * 128 + lane], a0);
      a1 = fmaf(xm, W1T[256 * 128 + 64 + lane], a1);
    }
    gh[wvl][lane]      = (float)tanh((double)(a0 + G_b1[lane]));
    gh[wvl][64 + lane] = (float)tanh((double)(a1 + G_b1[64 + lane]));
    float lg = 0.f;
    if (lane < 8)
      for (int o = 0; o < 128; ++o)         // exact sequential-o chain
        lg = fmaf(gh[wvl][o], G_W2[lane * 128 + o], lg);
    float v[8];
#pragma unroll
    for (int e = 0; e < 8; ++e) v[e] = __shfl(lg, e);
    if (lane == 0) {
#pragma unroll
      for (int e = 0; e < 8; ++e)
        v[e] = fminf(fmaxf((v[e] + G_b2[e]) / 0.7f, -10.f), 10.f);
      float tv[4]; int ti[4]; unsigned msk = 0;
      for (int kk = 0; kk < 4; ++kk) {
        float best = -1e30f; int bi = 0;
        for (int e = 0; e < 8; ++e)
          if (!((msk >> e) & 1u) && v[e] > best) { best = v[e]; bi = e; }
        tv[kk] = best; ti[kk] = bi; msk |= 1u << bi;
      }
      float mx = tv[0], den = 0.f, wk4[4];
#pragma unroll
      for (int kk = 0; kk < 4; ++kk) { wk4[kk] = expf(tv[kk] - mx); den += wk4[kk]; }
#pragma unroll
      for (int e = 0; e < 8; ++e) {
        float val = 0.f;
#pragma unroll
        for (int kk = 0; kk < 4; ++kk) if (ti[kk] == e) val = wk4[kk] / den;
        w8full[(size_t)T * 8 + e] = val;
      }
      float dall = 0.f, pe[8];
#pragma unroll
      for (int e = 0; e < 8; ++e) { pe[e] = expf(v[e] - mx); dall += pe[e]; }
      for (int e = 0; e < 8; ++e) atomicAdd(usage + e, pe[e] / dall);
    }
  }
}

// ============== moe v10 (round-12, unchanged) ==============
__global__ __launch_bounds__(512, 2) void moe_kernel(
    const float* __restrict__ x,
    const unsigned short* __restrict__ W1cat, const unsigned short* __restrict__ W2cat,
    const float* __restrict__ b1cat, const float* __restrict__ b2cat,
    const float* __restrict__ lng, const float* __restrict__ lnb,
    const float* __restrict__ bsc, const float* __restrict__ bbi,
    const float* __restrict__ w8full, float* __restrict__ out)
{
  __shared__ unsigned char smem[131072];    // W1L 64K | W2L 32K | HS 8x4K
  short8* W1L = (short8*)smem;
  short8* W2L = (short8*)(smem + 65536);
  unsigned char* HS = smem + 98304 + (threadIdx.x >> 6) * 4096;

  const int tid = threadIdx.x;
  const int wv = tid >> 6, lane = tid & 63;
  const int l15 = lane & 15, l4 = lane >> 4;
  const int tb = blockIdx.x * 128 + wv * 16;
  const short8* W1f = (const short8*)W1cat;
  const short8* W2f = (const short8*)W2cat;

  short8 A[8];
#pragma unroll
  for (int ks = 0; ks < 8; ++ks) {
    const float* xr = x + (size_t)(tb + l15) * 256 + ks * 32 + l4 * 8;
    float4 u = *(const float4*)xr, v = *(const float4*)(xr + 4);
    short8 a;
    a[0]=(short)f2bf(u.x); a[1]=(short)f2bf(u.y); a[2]=(short)f2bf(u.z); a[3]=(short)f2bf(u.w);
    a[4]=(short)f2bf(v.x); a[5]=(short)f2bf(v.y); a[6]=(short)f2bf(v.z); a[7]=(short)f2bf(v.w);
    A[ks] = a;
  }

  f32x4 zero = {0.f, 0.f, 0.f, 0.f};
  f32x4 pacc[8];
#pragma unroll
  for (int nt = 0; nt < 8; ++nt) pacc[nt] = zero;
  const float RS = 1.0f / sqrtf(1.0f + 1e-5f);

  short8 stg[12];
#pragma unroll
  for (int i = 0; i < 8; ++i) stg[i] = W1f[tid + i * 512];
#pragma unroll
  for (int i = 0; i < 4; ++i) stg[8 + i] = W2f[tid + i * 512];

  for (int g = 0; g < 9; ++g) {
    const int type = (g < 2) ? 0 : (g < 4) ? 1 : (g < 6) ? 2 : (g < 8) ? 3 : 4;
    const int g2 = (g < 4) ? g : ((g == 8) ? 6 : g - 2);

    __syncthreads();
#pragma unroll
    for (int i = 0; i < 8; ++i) W1L[tid + i * 512] = stg[i];
#pragma unroll
    for (int i = 0; i < 4; ++i) W2L[tid + i * 512] = stg[8 + i];
    if (g < 8) {
      int gn = g + 1;
      int g2n = (gn < 4) ? gn : ((gn == 8) ? 6 : gn - 2);
#pragma unroll
      for (int i = 0; i < 8; ++i) stg[i] = W1f[(size_t)gn * 4096 + tid + i * 512];
#pragma unroll
      for (int i = 0; i < 4; ++i) stg[8 + i] = W2f[(size_t)g2n * 2048 + tid + i * 512];
    }
    __syncthreads();

    f32x4 acc[8];
#pragma unroll
    for (int nt = 0; nt < 8; ++nt) acc[nt] = zero;
#pragma unroll
    for (int ks = 0; ks < 8; ++ks)
#pragma unroll
      for (int nt = 0; nt < 8; ++nt)
        acc[nt] = MFMA16(A[ks], W1L[(ks * 8 + nt) * 64 + lane], acc[nt]);

    const float* b1 = b1cat + g * 128;

    if (type == 2) {
#pragma unroll
      for (int r = 0; r < 4; ++r) {
        float wv_ = w8full[(size_t)(tb + l4 * 4 + r) * 8 + g];
#pragma unroll
        for (int nt = 0; nt < 8; ++nt) {
          float h = fgelu(acc[nt][r] + b1[nt * 16 + l15]);
          pacc[nt][r] += wv_ * h;
        }
      }
      continue;
    }
#pragma unroll
    for (int r = 0; r < 4; ++r)
#pragma unroll
      for (int nt = 0; nt < 8; ++nt) {
        float h = acc[nt][r] + b1[nt * 16 + l15];
        if (type == 0)      h = fmaxf(h, 0.f);
        else if (type == 1) {
          int col = (g - 2) * 128 + nt * 16 + l15;
          h = ftanh(h) * RS * bsc[col] + bbi[col];
        }
        else if (type == 3) h = fsilu(h);
        else                h = fmaxf(h, 0.f);
        acc[nt][r] = h;
      }
    if (type >= 3) {
      int li = (type == 4) ? 2 : (g - 6);
#pragma unroll
      for (int r = 0; r < 4; ++r) {
        float s1 = 0.f, s2 = 0.f;
#pragma unroll
        for (int nt = 0; nt < 8; ++nt) { float h = acc[nt][r]; s1 += h; s2 += h * h; }
        for (int m = 1; m <= 8; m <<= 1) { s1 += __shfl_xor(s1, m); s2 += __shfl_xor(s2, m); }
        float mu = s1 * (1.f / 128.f);
        float var = s2 * (1.f / 128.f) - mu * mu;
        float sc = __builtin_amdgcn_rsqf(var + 1e-5f);
#pragma unroll
        for (int nt = 0; nt < 8; ++nt) {
          int col = nt * 16 + l15;
          acc[nt][r] = (acc[nt][r] - mu) * sc * lng[li * 128 + col] + lnb[li * 128 + col];
        }
      }
    }
#pragma unroll
    for (int r = 0; r < 4; ++r) {
      int row = l4 * 4 + r;
#pragma unroll
      for (int nt = 0; nt < 8; ++nt) {
        int bytecol = (nt * 16 + l15) * 2;
        int addr = row * 256 + ((((bytecol >> 4) ^ (row & 7)) << 4) | (bytecol & 15));
        *(unsigned short*)(HS + addr) = f2bf(acc[nt][r]);
      }
    }
    short8 a2[4];
#pragma unroll
    for (int ks = 0; ks < 4; ++ks) {
      int ar = l15 * 256 + ((((ks * 4 + l4) ^ (l15 & 7)) << 4));
      a2[ks] = *(const short8*)(HS + ar);
    }
    f32x4 acc2[8];
#pragma unroll
    for (int nt = 0; nt < 8; ++nt) acc2[nt] = zero;
#pragma unroll
    for (int ks = 0; ks < 4; ++ks)
#pragma unroll
      for (int nt = 0; nt < 8; ++nt)
        acc2[nt] = MFMA16(a2[ks], W2L[(ks * 8 + nt) * 64 + lane], acc2[nt]);

    const float* b2 = b2cat + g2 * 128;
    if (type == 4) {
#pragma unroll
      for (int r = 0; r < 4; ++r) {
        int token = tb + l4 * 4 + r;
#pragma unroll
        for (int nt = 0; nt < 8; ++nt)
          out[(size_t)token * 128 + nt * 16 + l15] = acc2[nt][r] + b2[nt * 16 + l15];
      }
    } else {
#pragma unroll
      for (int r = 0; r < 4; ++r) {
        float wv_ = w8full[(size_t)(tb + l4 * 4 + r) * 8 + g];
#pragma unroll
        for (int nt = 0; nt < 8; ++nt)
          pacc[nt][r] += wv_ * (acc2[nt][r] + b2[nt * 16 + l15]);
      }
    }
  }
#pragma unroll
  for (int r = 0; r < 4; ++r) {
    int token = tb + l4 * 4 + r;
#pragma unroll
    for (int nt = 0; nt < 8; ++nt)
      out[4194304 + (size_t)token * 128 + nt * 16 + l15] = pacc[nt][r];
  }
}

// ============== aux scalar ==============
__global__ void aux_kernel(const float* __restrict__ usage, float* __restrict__ out) {
  if (threadIdx.x == 0 && blockIdx.x == 0) {
    float a = 0.f;
    for (int e = 0; e < 8; ++e) {
      float u = usage[e] * (1.0f / 32768.0f);
      a += 0.125f * (logf(0.125f) - logf(u + 1e-10f));
    }
    out[8388608] = a * 0.125f;
  }
}

extern "C" void kernel_launch(void* const* d_in, const int* in_sizes, int n_in,
                              void* d_out, int out_size, void* d_ws, size_t ws_size,
                              hipStream_t stream) {
  (void)in_sizes; (void)n_in; (void)out_size; (void)ws_size;
  const float* x    = (const float*)d_in[0];
  const int*   mod  = (const int*)d_in[1];
  const float* A_W1 = (const float*)d_in[2];
  const float* A_b1 = (const float*)d_in[3];
  const float* A_W2 = (const float*)d_in[4];
  const float* A_b2 = (const float*)d_in[5];
  const float* B_W1 = (const float*)d_in[6];
  const float* B_b1 = (const float*)d_in[7];
  const float* B_g  = (const float*)d_in[8];
  const float* B_be = (const float*)d_in[9];
  const float* B_W2 = (const float*)d_in[10];
  const float* B_b2 = (const float*)d_in[11];
  const float* C_cw = (const float*)d_in[12];
  const float* C_cb = (const float*)d_in[13];
  const float* C_W  = (const float*)d_in[14];
  const float* C_b  = (const float*)d_in[15];
  const float* D_W1 = (const float*)d_in[16];
  const float* D_b1 = (const float*)d_in[17];
  const float* D_g  = (const float*)d_in[18];
  const float* D_be = (const float*)d_in[19];
  const float* D_W2 = (const float*)d_in[20];
  const float* D_b2 = (const float*)d_in[21];
  const float* S_W1 = (const float*)d_in[22];
  const float* S_b1 = (const float*)d_in[23];
  const float* S_g  = (const float*)d_in[24];
  const float* S_be = (const float*)d_in[25];
  const float* S_W2 = (const float*)d_in[26];
  const float* S_b2 = (const float*)d_in[27];
  const float* G_W1 = (const float*)d_in[28];
  const float* G_b1 = (const float*)d_in[29];
  const float* G_W2 = (const float*)d_in[30];
  const float* G_b2 = (const float*)d_in[31];

  char* ws = (char*)d_ws;
  unsigned short* W1cat = (unsigned short*)(ws + OFF_W1CAT);
  unsigned short* W2cat = (unsigned short*)(ws + OFF_W2CAT);
  float* W1T    = (float*)(ws + OFF_W1T);
  unsigned short* GW1HF = (unsigned short*)(ws + OFF_GW1HF);
  unsigned short* GW1LF = (unsigned short*)(ws + OFF_GW1LF);
  float* b1cat  = (float*)(ws + OFF_B1);
  float* b2cat  = (float*)(ws + OFF_B2);
  float* lng    = (float*)(ws + OFF_LNG);
  float* lnb    = (float*)(ws + OFF_LNB);
  float* bsc    = (float*)(ws + OFF_BSC);
  float* bbi    = (float*)(ws + OFF_BBI);
  float* usage  = (float*)(ws + OFF_USAGE);
  float* w8full = (float*)(ws + OFF_W8);
  int*   cnt    = (int*)(ws + OFF_CNT);
  int*   list   = (int*)(ws + OFF_LIST);
  float* out    = (float*)d_out;

  prep_kernel<<<1870, 256, 0, stream>>>(A_W1, A_b1, A_W2, A_b2, B_W1, B_b1, B_g, B_be,
      B_W2, B_b2, C_cw, C_cb, C_W, C_b, D_W1, D_b1, D_g, D_be, D_W2, D_b2,
      S_W1, S_b1, S_g, S_be, S_W2, S_b2, G_W1,
      W1cat, W2cat, W1T, GW1HF, GW1LF, b1cat, b2cat, lng, lnb, bsc, bbi, usage);
  prep2_kernel<<<4, 256, 0, stream>>>(C_cw, C_cb, C_W, b1cat, cnt);
  gate_fast_kernel<<<512, 512, 0, stream>>>(x, mod, GW1HF, GW1LF, G_W1, G_b1,
      G_W2, G_b2, w8full, usage, cnt, list);
  gate_slow_kernel<<<256, 256, 0, stream>>>(x, mod, W1T, G_b1, G_W2, G_b2,
      cnt, list, w8full, usage);
  moe_kernel<<<256, 512, 0, stream>>>(x, W1cat, W2cat, b1cat, b2cat, lng, lnb,
      bsc, bbi, w8full, out);
  aux_kernel<<<1, 64, 0, stream>>>(usage, out);
}

// Round 15
// 402.082 us; speedup vs baseline: 1.3461x; 1.0160x over previous
//
#include <hip/hip_runtime.h>
#include <hip/hip_bf16.h>
#include <math.h>

typedef __attribute__((ext_vector_type(8))) short short8;      // 8 bf16 (4 VGPRs)
typedef __attribute__((ext_vector_type(4))) float f32x4;       // MFMA acc
typedef __attribute__((ext_vector_type(4))) unsigned short us4;

#define MFMA16(a,b,c) __builtin_amdgcn_mfma_f32_16x16x32_bf16((a),(b),(c),0,0,0)

// ---------------- workspace layout (bytes) ----------------
#define OFF_W1CAT   0u         // bf16 frag [9][8][8][64][8]
#define OFF_W2CAT   589824u    // bf16 frag [7][4][8][64][8]
#define OFF_B1      950272u    // f32 [9][128]
#define OFF_B2      954880u    // f32 [7][128]
#define OFF_LNG     958464u    // f32 [3][128]
#define OFF_LNB     960000u    // f32 [3][128]
#define OFF_BSC     961536u    // f32 [2][128]
#define OFF_BBI     962560u    // f32 [2][128]
#define OFF_USAGE   963584u    // f32 [8]
#define OFF_W8      963712u    // f32 [32768][8]
#define OFF_W1T     2012288u   // f32 [257][128]
#define OFF_GW1HF   2143872u   // bf16 frag [8][8][64][8]
#define OFF_GW1LF   2209408u
#define OFF_CNT     2274944u   // int
#define OFF_LIST    2275008u   // int [32768]

#define DELTA 2e-3f

__device__ __forceinline__ unsigned short f2bf(float f) {
  union { float f; unsigned u; } v; v.f = f;
  return (unsigned short)((v.u + 0x7fffu + ((v.u >> 16) & 1u)) >> 16);
}
__device__ __forceinline__ float bf2f(unsigned short b) {
  union { unsigned u; float f; } v; v.u = ((unsigned)b) << 16; return v.f;
}
__device__ __forceinline__ float frcp(float x) { return __builtin_amdgcn_rcpf(x); }
__device__ __forceinline__ float ftanh(float x) {          // moe epilogue
  float ax = fabsf(x);
  float t = __expf(-2.f * ax);
  float r = (1.f - t) * frcp(1.f + t);
  return copysignf(r, x);
}
__device__ __forceinline__ float ftanh_acc(float x) {      // gate fast path
  float ax = fabsf(x);
  float t = __expf(-2.f * ax);
  float r = (1.f - t) / (1.f + t);
  return copysignf(r, x);
}
__device__ __forceinline__ float fsilu(float x) {
  return x * frcp(1.f + __expf(-x));
}
__device__ __forceinline__ float fgelu(float x) {
  float ax = fabsf(x) * 0.70710678118654752f;
  float t = frcp(fmaf(0.3275911f, ax, 1.f));
  float p = fmaf(t, 1.061405429f, -1.453152027f);
  p = fmaf(t, p, 1.421413741f);
  p = fmaf(t, p, -0.284496736f);
  p = fmaf(t, p, 0.254829592f);
  p *= t;
  float erfv = copysignf(fmaf(-p, __expf(-ax * ax), 1.f), x);
  return 0.5f * x * (1.f + erfv);
}

// ============== prep ==============
__global__ __launch_bounds__(256) void prep_kernel(
    const float* __restrict__ A_W1, const float* __restrict__ A_b1,
    const float* __restrict__ A_W2, const float* __restrict__ A_b2,
    const float* __restrict__ B_W1, const float* __restrict__ B_b1,
    const float* __restrict__ B_g,  const float* __restrict__ B_be,
    const float* __restrict__ B_W2, const float* __restrict__ B_b2,
    const float* __restrict__ C_cw, const float* __restrict__ C_cb,
    const float* __restrict__ C_W,  const float* __restrict__ C_b,
    const float* __restrict__ D_W1, const float* __restrict__ D_b1,
    const float* __restrict__ D_g,  const float* __restrict__ D_be,
    const float* __restrict__ D_W2, const float* __restrict__ D_b2,
    const float* __restrict__ S_W1, const float* __restrict__ S_b1,
    const float* __restrict__ S_g,  const float* __restrict__ S_be,
    const float* __restrict__ S_W2, const float* __restrict__ S_b2,
    const float* __restrict__ G_W1,
    unsigned short* __restrict__ W1cat, unsigned short* __restrict__ W2cat,
    float* __restrict__ W1T,
    unsigned short* __restrict__ GW1HF, unsigned short* __restrict__ GW1LF,
    float* __restrict__ b1cat, float* __restrict__ b2cat,
    float* __restrict__ lng, float* __restrict__ lnb,
    float* __restrict__ bsc, float* __restrict__ bbi,
    float* __restrict__ usage)
{
  int tid = blockIdx.x * 256 + threadIdx.x;
  if (tid < 294912) {                       // W1cat, fragment order
    int g = tid >> 15, rem = tid & 32767;
    int j = rem & 7, lane = (rem >> 3) & 63, nt = (rem >> 9) & 7, ks = rem >> 12;
    int p = nt * 16 + (lane & 15);
    int k = ks * 32 + (lane >> 4) * 8 + j;
    int src = p * 256 + k;
    float v;
    if (g < 2)      v = A_W1[g * 32768 + src];
    else if (g < 4) v = B_W1[(g - 2) * 32768 + src];
    else if (g < 6) {
      int e = g - 4;
      v = 0.f;
      for (int c = 0; c < 4; ++c)
        for (int jj = 0; jj < 3; ++jj) {
          int h = k + 1 - jj;
          if (h >= 0 && h < 256)
            v += C_cw[e*12 + c*3 + jj] * C_W[e*131072 + p*1024 + c*256 + h];
        }
    }
    else if (g < 8) v = D_W1[(g - 6) * 32768 + src];
    else            v = S_W1[src];
    W1cat[tid] = f2bf(v);
    return;
  }
  tid -= 294912;
  if (tid < 114688) {                       // W2cat, fragment order
    int g = tid >> 14, rem = tid & 16383;
    int j = rem & 7, lane = (rem >> 3) & 63, nt = (rem >> 9) & 7, ks = rem >> 12;
    int p = nt * 16 + (lane & 15);
    int k = ks * 32 + (lane >> 4) * 8 + j;
    int src = p * 128 + k;
    float v;
    if (g < 2)      v = A_W2[g * 16384 + src];
    else if (g < 4) v = B_W2[(g - 2) * 16384 + src];
    else if (g < 6) v = D_W2[(g - 4) * 16384 + src];
    else            v = S_W2[src];
    W2cat[tid] = f2bf(v);
    return;
  }
  tid -= 114688;
  if (tid < 32896) {                        // W1T[k][o] = G_W1[o][k]
    int k = tid / 128, o = tid % 128;
    W1T[tid] = G_W1[o * 257 + k];
    return;
  }
  tid -= 32896;
  if (tid < 32768) {                        // gate W1 hi/lo, fragment order
    int j = tid & 7, lane = (tid >> 3) & 63, nt = (tid >> 9) & 7, ks = tid >> 12;
    int o = nt * 16 + (lane & 15);
    int k = ks * 32 + (lane >> 4) * 8 + j;
    float v = G_W1[o * 257 + k];
    unsigned short h = f2bf(v);
    GW1HF[tid] = h;
    GW1LF[tid] = f2bf(v - bf2f(h));
    return;
  }
  tid -= 32768;
  if (tid < 1152) {                         // b1cat (C fold added by prep2)
    int g = tid / 128, p = tid % 128;
    float v;
    if (g < 2)      v = A_b1[tid];
    else if (g < 4) v = B_b1[p + (g - 2) * 128];
    else if (g < 6) v = C_b[(g - 4) * 128 + p];
    else if (g < 8) v = D_b1[p + (g - 6) * 128];
    else            v = S_b1[p];
    b1cat[tid] = v;
    return;
  }
  tid -= 1152;
  if (tid < 896) {                          // b2cat
    int g = tid / 128, p = tid % 128;
    float v;
    if (g < 2)      v = A_b2[tid];
    else if (g < 4) v = B_b2[p + (g - 2) * 128];
    else if (g < 6) v = D_b2[p + (g - 4) * 128];
    else            v = S_b2[p];
    b2cat[tid] = v;
    return;
  }
  tid -= 896;
  if (tid < 768) {
    if (tid < 384) {
      int j = tid / 128, p = tid % 128;
      lng[tid] = (j < 2) ? D_g[tid] : S_g[p];
    } else {
      int q = tid - 384; int j = q / 128, p = q % 128;
      lnb[q] = (j < 2) ? D_be[q] : S_be[p];
    }
    return;
  }
  tid -= 768;
  if (tid < 512) {
    if (tid < 256) bsc[tid] = B_g[tid];
    else           bbi[tid - 256] = B_be[tid - 256];
    return;
  }
  tid -= 512;
  if (tid < 8) usage[tid] = 0.f;
}

// prep2: conv-bias fold + counter zero
__global__ __launch_bounds__(256) void prep2_kernel(
    const float* __restrict__ C_cw_unused, const float* __restrict__ C_cb,
    const float* __restrict__ C_W, float* __restrict__ b1cat, int* __restrict__ cnt)
{
  int tid = blockIdx.x * 256 + threadIdx.x;
  if (tid == 0) *cnt = 0;
  int e = tid >> 9, rem = tid & 511;
  int p = rem >> 2, c = rem & 3;
  const float4* row = (const float4*)(C_W + e*131072 + p*1024 + c*256);
  float s = 0.f;
  for (int q = 0; q < 64; ++q) {
    float4 v = row[q];
    s += v.x + v.y + v.z + v.w;
  }
  atomicAdd(&b1cat[(4 + e) * 128 + p], C_cb[e * 4 + c] * s);
}

// ============== gate_fast: MFMA bf16x3, o-half split, flag compaction ==============
__global__ __launch_bounds__(512, 4) void gate_fast_kernel(
    const float* __restrict__ x, const int* __restrict__ modality,
    const unsigned short* __restrict__ GW1HF, const unsigned short* __restrict__ GW1LF,
    const float* __restrict__ G_W1, const float* __restrict__ G_b1,
    const float* __restrict__ G_W2, const float* __restrict__ G_b2,
    float* __restrict__ w8full, float* __restrict__ usage,
    int* __restrict__ cnt, int* __restrict__ list)
{
  __shared__ float gh[64][132];
  __shared__ float lgs[64][9];
  const int tid = threadIdx.x;
  const int wv = tid >> 6, lane = tid & 63;
  const int l15 = lane & 15, l4 = lane >> 4;
  const int tg = wv >> 1, half = wv & 1;
  const int tb = blockIdx.x * 64;
  const int tw = tb + tg * 16;

  const short8* srcH = (const short8*)GW1HF;
  const short8* srcL = (const short8*)GW1LF;

  short8 XH[8], XL[8];
#pragma unroll
  for (int ks = 0; ks < 8; ++ks) {
    const float* xr = x + (size_t)(tw + l15) * 256 + ks * 32 + l4 * 8;
    float4 u = *(const float4*)xr, v = *(const float4*)(xr + 4);
    float xv[8] = {u.x, u.y, u.z, u.w, v.x, v.y, v.z, v.w};
    short8 hh, ll;
#pragma unroll
    for (int j2 = 0; j2 < 8; ++j2) {
      unsigned short h = f2bf(xv[j2]);
      hh[j2] = (short)h;
      ll[j2] = (short)f2bf(xv[j2] - bf2f(h));
    }
    XH[ks] = hh; XL[ks] = ll;
  }

  f32x4 zero = {0.f, 0.f, 0.f, 0.f};
  f32x4 acc[4];
#pragma unroll
  for (int n = 0; n < 4; ++n) acc[n] = zero;
#pragma unroll
  for (int ks = 0; ks < 8; ++ks) {
#pragma unroll
    for (int n = 0; n < 4; ++n) {
      int fi = ks * 512 + (half * 4 + n) * 64 + lane;
      short8 bh = srcH[fi];
      short8 bl = srcL[fi];
      acc[n] = MFMA16(XH[ks], bh, acc[n]);
      acc[n] = MFMA16(XH[ks], bl, acc[n]);
      acc[n] = MFMA16(XL[ks], bh, acc[n]);
    }
  }
  float mf[4];
#pragma unroll
  for (int r = 0; r < 4; ++r) mf[r] = (float)modality[tw + l4 * 4 + r];
#pragma unroll
  for (int n = 0; n < 4; ++n) {
    int o = (half * 4 + n) * 16 + l15;
    float wm = G_W1[o * 257 + 256];
    float b = G_b1[o];
#pragma unroll
    for (int r = 0; r < 4; ++r)
      gh[tg * 16 + l4 * 4 + r][o] = ftanh_acc(fmaf(mf[r], wm, acc[n][r]) + b);
  }
  __syncthreads();

  {                                         // layer 2: thread = (token, expert)
    int t2 = tid >> 3, e2 = tid & 7;
    float lg = 0.f;
    for (int o2 = 0; o2 < 128; ++o2)
      lg = fmaf(gh[t2][o2], G_W2[e2 * 128 + o2], lg);
    float s = (lg + G_b2[e2]) / 0.7f;
    lgs[t2][e2] = fminf(fmaxf(s, -10.f), 10.f);
  }
  __syncthreads();

  if (wv == 0) {                            // 64 tokens on 64 lanes
    int token = tb + lane;
    float v[8];
#pragma unroll
    for (int e = 0; e < 8; ++e) v[e] = lgs[lane][e];
    float tv[5]; int ti[5]; unsigned msk = 0;
    for (int kk = 0; kk < 5; ++kk) {
      float best = -1e30f; int bi = 0;
      for (int e = 0; e < 8; ++e)
        if (!((msk >> e) & 1u) && v[e] > best) { best = v[e]; bi = e; }
      tv[kk] = best; ti[kk] = bi; msk |= 1u << bi;
    }
    float uw[8];
#pragma unroll
    for (int e = 0; e < 8; ++e) uw[e] = 0.f;
    if (tv[3] - tv[4] < DELTA) {            // near-tie -> np-exact recompute later
      int idx = atomicAdd(cnt, 1);
      list[idx] = token;
    } else {
      float mx = tv[0], den = 0.f, wk4[4];
#pragma unroll
      for (int kk = 0; kk < 4; ++kk) { wk4[kk] = expf(tv[kk] - mx); den += wk4[kk]; }
#pragma unroll
      for (int e = 0; e < 8; ++e) {
        float val = 0.f;
#pragma unroll
        for (int kk = 0; kk < 4; ++kk) if (ti[kk] == e) val = wk4[kk] / den;
        w8full[(size_t)token * 8 + e] = val;
      }
      float dall = 0.f, pe[8];
#pragma unroll
      for (int e = 0; e < 8; ++e) { pe[e] = expf(v[e] - mx); dall += pe[e]; }
#pragma unroll
      for (int e = 0; e < 8; ++e) uw[e] = pe[e] / dall;
    }
    for (int m = 1; m <= 32; m <<= 1)
#pragma unroll
      for (int e = 0; e < 8; ++e) uw[e] += __shfl_xor(uw[e], m);
    if (lane == 0)
      for (int e = 0; e < 8; ++e) atomicAdd(usage + e, uw[e]);
  }
}

// ============== gate_slow v2: LDS-resident W1T; np-exact chains ==============
// Block stages W1T (131KB) + G_W2 once; 4 waves each process flagged tokens.
// Per (t,o) arithmetic bit-identical to round-12 oracle (LDS copies same values).
__global__ __launch_bounds__(256) void gate_slow_kernel(
    const float* __restrict__ x, const int* __restrict__ modality,
    const float* __restrict__ W1T, const float* __restrict__ G_b1,
    const float* __restrict__ G_W2, const float* __restrict__ G_b2,
    const int* __restrict__ cnt, const int* __restrict__ list,
    float* __restrict__ w8full, float* __restrict__ usage)
{
  __shared__ float w1l[32896];              // [257][128] f32, 131584 B
  __shared__ float w2l[8][132];
  __shared__ float xs[4][256];
  __shared__ float gh[4][128];
  const int n = *cnt;
  if (blockIdx.x * 4 >= n) return;          // no tokens for this block

  for (int idx = threadIdx.x; idx < 8224; idx += 256)
    ((float4*)w1l)[idx] = ((const float4*)W1T)[idx];
  for (int idx = threadIdx.x; idx < 1024; idx += 256)
    w2l[idx >> 7][idx & 127] = G_W2[idx];
  __syncthreads();

  const int wvl = threadIdx.x >> 6, lane = threadIdx.x & 63;
  for (int i = blockIdx.x * 4 + wvl; i < n; i += 1024) {
    const int T = __builtin_amdgcn_readfirstlane(list[i]);
#pragma unroll
    for (int q = 0; q < 4; ++q)
      xs[wvl][q * 64 + lane] = x[(size_t)T * 256 + q * 64 + lane];
    float a0 = 0.f, a1 = 0.f;
#pragma unroll 8
    for (int k = 0; k < 256; ++k) {         // exact sequential-k chain (np order)
      float xv = xs[wvl][k];
      a0 = fmaf(xv, w1l[k * 128 + lane], a0);
      a1 = fmaf(xv, w1l[k * 128 + 64 + lane], a1);
    }
    {
      float xm = (float)modality[T];
      a0 = fmaf(xm, w1l[256 * 128 + lane], a0);
      a1 = fmaf(xm, w1l[256 * 128 + 64 + lane], a1);
    }
    gh[wvl][lane]      = (float)tanh((double)(a0 + G_b1[lane]));
    gh[wvl][64 + lane] = (float)tanh((double)(a1 + G_b1[64 + lane]));
    float lg = 0.f;
    if (lane < 8)
      for (int o = 0; o < 128; ++o)         // exact sequential-o chain
        lg = fmaf(gh[wvl][o], w2l[lane][o], lg);
    float v[8];
#pragma unroll
    for (int e = 0; e < 8; ++e) v[e] = __shfl(lg, e);
    if (lane == 0) {
#pragma unroll
      for (int e = 0; e < 8; ++e)
        v[e] = fminf(fmaxf((v[e] + G_b2[e]) / 0.7f, -10.f), 10.f);
      float tv[4]; int ti[4]; unsigned msk = 0;
      for (int kk = 0; kk < 4; ++kk) {
        float best = -1e30f; int bi = 0;
        for (int e = 0; e < 8; ++e)
          if (!((msk >> e) & 1u) && v[e] > best) { best = v[e]; bi = e; }
        tv[kk] = best; ti[kk] = bi; msk |= 1u << bi;
      }
      float mx = tv[0], den = 0.f, wk4[4];
#pragma unroll
      for (int kk = 0; kk < 4; ++kk) { wk4[kk] = expf(tv[kk] - mx); den += wk4[kk]; }
#pragma unroll
      for (int e = 0; e < 8; ++e) {
        float val = 0.f;
#pragma unroll
        for (int kk = 0; kk < 4; ++kk) if (ti[kk] == e) val = wk4[kk] / den;
        w8full[(size_t)T * 8 + e] = val;
      }
      float dall = 0.f, pe[8];
#pragma unroll
      for (int e = 0; e < 8; ++e) { pe[e] = expf(v[e] - mx); dall += pe[e]; }
      for (int e = 0; e < 8; ++e) atomicAdd(usage + e, pe[e] / dall);
    }
  }
}

// ============== moe v10 (round-12, unchanged) ==============
__global__ __launch_bounds__(512, 2) void moe_kernel(
    const float* __restrict__ x,
    const unsigned short* __restrict__ W1cat, const unsigned short* __restrict__ W2cat,
    const float* __restrict__ b1cat, const float* __restrict__ b2cat,
    const float* __restrict__ lng, const float* __restrict__ lnb,
    const float* __restrict__ bsc, const float* __restrict__ bbi,
    const float* __restrict__ w8full, float* __restrict__ out)
{
  __shared__ unsigned char smem[131072];    // W1L 64K | W2L 32K | HS 8x4K
  short8* W1L = (short8*)smem;
  short8* W2L = (short8*)(smem + 65536);
  unsigned char* HS = smem + 98304 + (threadIdx.x >> 6) * 4096;

  const int tid = threadIdx.x;
  const int wv = tid >> 6, lane = tid & 63;
  const int l15 = lane & 15, l4 = lane >> 4;
  const int tb = blockIdx.x * 128 + wv * 16;
  const short8* W1f = (const short8*)W1cat;
  const short8* W2f = (const short8*)W2cat;

  short8 A[8];
#pragma unroll
  for (int ks = 0; ks < 8; ++ks) {
    const float* xr = x + (size_t)(tb + l15) * 256 + ks * 32 + l4 * 8;
    float4 u = *(const float4*)xr, v = *(const float4*)(xr + 4);
    short8 a;
    a[0]=(short)f2bf(u.x); a[1]=(short)f2bf(u.y); a[2]=(short)f2bf(u.z); a[3]=(short)f2bf(u.w);
    a[4]=(short)f2bf(v.x); a[5]=(short)f2bf(v.y); a[6]=(short)f2bf(v.z); a[7]=(short)f2bf(v.w);
    A[ks] = a;
  }

  f32x4 zero = {0.f, 0.f, 0.f, 0.f};
  f32x4 pacc[8];
#pragma unroll
  for (int nt = 0; nt < 8; ++nt) pacc[nt] = zero;
  const float RS = 1.0f / sqrtf(1.0f + 1e-5f);

  short8 stg[12];
#pragma unroll
  for (int i = 0; i < 8; ++i) stg[i] = W1f[tid + i * 512];
#pragma unroll
  for (int i = 0; i < 4; ++i) stg[8 + i] = W2f[tid + i * 512];

  for (int g = 0; g < 9; ++g) {
    const int type = (g < 2) ? 0 : (g < 4) ? 1 : (g < 6) ? 2 : (g < 8) ? 3 : 4;
    const int g2 = (g < 4) ? g : ((g == 8) ? 6 : g - 2);

    __syncthreads();
#pragma unroll
    for (int i = 0; i < 8; ++i) W1L[tid + i * 512] = stg[i];
#pragma unroll
    for (int i = 0; i < 4; ++i) W2L[tid + i * 512] = stg[8 + i];
    if (g < 8) {
      int gn = g + 1;
      int g2n = (gn < 4) ? gn : ((gn == 8) ? 6 : gn - 2);
#pragma unroll
      for (int i = 0; i < 8; ++i) stg[i] = W1f[(size_t)gn * 4096 + tid + i * 512];
#pragma unroll
      for (int i = 0; i < 4; ++i) stg[8 + i] = W2f[(size_t)g2n * 2048 + tid + i * 512];
    }
    __syncthreads();

    f32x4 acc[8];
#pragma unroll
    for (int nt = 0; nt < 8; ++nt) acc[nt] = zero;
#pragma unroll
    for (int ks = 0; ks < 8; ++ks)
#pragma unroll
      for (int nt = 0; nt < 8; ++nt)
        acc[nt] = MFMA16(A[ks], W1L[(ks * 8 + nt) * 64 + lane], acc[nt]);

    const float* b1 = b1cat + g * 128;

    if (type == 2) {
#pragma unroll
      for (int r = 0; r < 4; ++r) {
        float wv_ = w8full[(size_t)(tb + l4 * 4 + r) * 8 + g];
#pragma unroll
        for (int nt = 0; nt < 8; ++nt) {
          float h = fgelu(acc[nt][r] + b1[nt * 16 + l15]);
          pacc[nt][r] += wv_ * h;
        }
      }
      continue;
    }
#pragma unroll
    for (int r = 0; r < 4; ++r)
#pragma unroll
      for (int nt = 0; nt < 8; ++nt) {
        float h = acc[nt][r] + b1[nt * 16 + l15];
        if (type == 0)      h = fmaxf(h, 0.f);
        else if (type == 1) {
          int col = (g - 2) * 128 + nt * 16 + l15;
          h = ftanh(h) * RS * bsc[col] + bbi[col];
        }
        else if (type == 3) h = fsilu(h);
        else                h = fmaxf(h, 0.f);
        acc[nt][r] = h;
      }
    if (type >= 3) {
      int li = (type == 4) ? 2 : (g - 6);
#pragma unroll
      for (int r = 0; r < 4; ++r) {
        float s1 = 0.f, s2 = 0.f;
#pragma unroll
        for (int nt = 0; nt < 8; ++nt) { float h = acc[nt][r]; s1 += h; s2 += h * h; }
        for (int m = 1; m <= 8; m <<= 1) { s1 += __shfl_xor(s1, m); s2 += __shfl_xor(s2, m); }
        float mu = s1 * (1.f / 128.f);
        float var = s2 * (1.f / 128.f) - mu * mu;
        float sc = __builtin_amdgcn_rsqf(var + 1e-5f);
#pragma unroll
        for (int nt = 0; nt < 8; ++nt) {
          int col = nt * 16 + l15;
          acc[nt][r] = (acc[nt][r] - mu) * sc * lng[li * 128 + col] + lnb[li * 128 + col];
        }
      }
    }
#pragma unroll
    for (int r = 0; r < 4; ++r) {
      int row = l4 * 4 + r;
#pragma unroll
      for (int nt = 0; nt < 8; ++nt) {
        int bytecol = (nt * 16 + l15) * 2;
        int addr = row * 256 + ((((bytecol >> 4) ^ (row & 7)) << 4) | (bytecol & 15));
        *(unsigned short*)(HS + addr) = f2bf(acc[nt][r]);
      }
    }
    short8 a2[4];
#pragma unroll
    for (int ks = 0; ks < 4; ++ks) {
      int ar = l15 * 256 + ((((ks * 4 + l4) ^ (l15 & 7)) << 4));
      a2[ks] = *(const short8*)(HS + ar);
    }
    f32x4 acc2[8];
#pragma unroll
    for (int nt = 0; nt < 8; ++nt) acc2[nt] = zero;
#pragma unroll
    for (int ks = 0; ks < 4; ++ks)
#pragma unroll
      for (int nt = 0; nt < 8; ++nt)
        acc2[nt] = MFMA16(a2[ks], W2L[(ks * 8 + nt) * 64 + lane], acc2[nt]);

    const float* b2 = b2cat + g2 * 128;
    if (type == 4) {
#pragma unroll
      for (int r = 0; r < 4; ++r) {
        int token = tb + l4 * 4 + r;
#pragma unroll
        for (int nt = 0; nt < 8; ++nt)
          out[(size_t)token * 128 + nt * 16 + l15] = acc2[nt][r] + b2[nt * 16 + l15];
      }
    } else {
#pragma unroll
      for (int r = 0; r < 4; ++r) {
        float wv_ = w8full[(size_t)(tb + l4 * 4 + r) * 8 + g];
#pragma unroll
        for (int nt = 0; nt < 8; ++nt)
          pacc[nt][r] += wv_ * (acc2[nt][r] + b2[nt * 16 + l15]);
      }
    }
  }
#pragma unroll
  for (int r = 0; r < 4; ++r) {
    int token = tb + l4 * 4 + r;
#pragma unroll
    for (int nt = 0; nt < 8; ++nt)
      out[4194304 + (size_t)token * 128 + nt * 16 + l15] = pacc[nt][r];
  }
}

// ============== aux scalar ==============
__global__ void aux_kernel(const float* __restrict__ usage, float* __restrict__ out) {
  if (threadIdx.x == 0 && blockIdx.x == 0) {
    float a = 0.f;
    for (int e = 0; e < 8; ++e) {
      float u = usage[e] * (1.0f / 32768.0f);
      a += 0.125f * (logf(0.125f) - logf(u + 1e-10f));
    }
    out[8388608] = a * 0.125f;
  }
}

extern "C" void kernel_launch(void* const* d_in, const int* in_sizes, int n_in,
                              void* d_out, int out_size, void* d_ws, size_t ws_size,
                              hipStream_t stream) {
  (void)in_sizes; (void)n_in; (void)out_size; (void)ws_size;
  const float* x    = (const float*)d_in[0];
  const int*   mod  = (const int*)d_in[1];
  const float* A_W1 = (const float*)d_in[2];
  const float* A_b1 = (const float*)d_in[3];
  const float* A_W2 = (const float*)d_in[4];
  const float* A_b2 = (const float*)d_in[5];
  const float* B_W1 = (const float*)d_in[6];
  const float* B_b1 = (const float*)d_in[7];
  const float* B_g  = (const float*)d_in[8];
  const float* B_be = (const float*)d_in[9];
  const float* B_W2 = (const float*)d_in[10];
  const float* B_b2 = (const float*)d_in[11];
  const float* C_cw = (const float*)d_in[12];
  const float* C_cb = (const float*)d_in[13];
  const float* C_W  = (const float*)d_in[14];
  const float* C_b  = (const float*)d_in[15];
  const float* D_W1 = (const float*)d_in[16];
  const float* D_b1 = (const float*)d_in[17];
  const float* D_g  = (const float*)d_in[18];
  const float* D_be = (const float*)d_in[19];
  const float* D_W2 = (const float*)d_in[20];
  const float* D_b2 = (const float*)d_in[21];
  const float* S_W1 = (const float*)d_in[22];
  const float* S_b1 = (const float*)d_in[23];
  const float* S_g  = (const float*)d_in[24];
  const float* S_be = (const float*)d_in[25];
  const float* S_W2 = (const float*)d_in[26];
  const float* S_b2 = (const float*)d_in[27];
  const float* G_W1 = (const float*)d_in[28];
  const float* G_b1 = (const float*)d_in[29];
  const float* G_W2 = (const float*)d_in[30];
  const float* G_b2 = (const float*)d_in[31];

  char* ws = (char*)d_ws;
  unsigned short* W1cat = (unsigned short*)(ws + OFF_W1CAT);
  unsigned short* W2cat = (unsigned short*)(ws + OFF_W2CAT);
  float* W1T    = (float*)(ws + OFF_W1T);
  unsigned short* GW1HF = (unsigned short*)(ws + OFF_GW1HF);
  unsigned short* GW1LF = (unsigned short*)(ws + OFF_GW1LF);
  float* b1cat  = (float*)(ws + OFF_B1);
  float* b2cat  = (float*)(ws + OFF_B2);
  float* lng    = (float*)(ws + OFF_LNG);
  float* lnb    = (float*)(ws + OFF_LNB);
  float* bsc    = (float*)(ws + OFF_BSC);
  float* bbi    = (float*)(ws + OFF_BBI);
  float* usage  = (float*)(ws + OFF_USAGE);
  float* w8full = (float*)(ws + OFF_W8);
  int*   cnt    = (int*)(ws + OFF_CNT);
  int*   list   = (int*)(ws + OFF_LIST);
  float* out    = (float*)d_out;

  prep_kernel<<<1870, 256, 0, stream>>>(A_W1, A_b1, A_W2, A_b2, B_W1, B_b1, B_g, B_be,
      B_W2, B_b2, C_cw, C_cb, C_W, C_b, D_W1, D_b1, D_g, D_be, D_W2, D_b2,
      S_W1, S_b1, S_g, S_be, S_W2, S_b2, G_W1,
      W1cat, W2cat, W1T, GW1HF, GW1LF, b1cat, b2cat, lng, lnb, bsc, bbi, usage);
  prep2_kernel<<<4, 256, 0, stream>>>(C_cw, C_cb, C_W, b1cat, cnt);
  gate_fast_kernel<<<512, 512, 0, stream>>>(x, mod, GW1HF, GW1LF, G_W1, G_b1,
      G_W2, G_b2, w8full, usage, cnt, list);
  gate_slow_kernel<<<256, 256, 0, stream>>>(x, mod, W1T, G_b1, G_W2, G_b2,
      cnt, list, w8full, usage);
  moe_kernel<<<256, 512, 0, stream>>>(x, W1cat, W2cat, b1cat, b2cat, lng, lnb,
      bsc, bbi, w8full, out);
  aux_kernel<<<1, 64, 0, stream>>>(usage, out);
}

// Round 16
// 237.215 us; speedup vs baseline: 2.2817x; 1.6950x over previous
//
#include <hip/hip_runtime.h>
#include <hip/hip_bf16.h>
#include <math.h>

typedef __attribute__((ext_vector_type(8))) short short8;      // 8 bf16 (4 VGPRs)
typedef __attribute__((ext_vector_type(4))) float f32x4;       // MFMA acc
typedef __attribute__((ext_vector_type(4))) unsigned short us4;

#define MFMA16(a,b,c) __builtin_amdgcn_mfma_f32_16x16x32_bf16((a),(b),(c),0,0,0)

// ---------------- workspace layout (bytes) ----------------
#define OFF_W1CAT   0u         // bf16 frag [9][8][8][64][8]
#define OFF_W2CAT   589824u    // bf16 frag [7][4][8][64][8]
#define OFF_B1      950272u    // f32 [9][128]
#define OFF_B2      954880u    // f32 [7][128]
#define OFF_LNG     958464u    // f32 [3][128]
#define OFF_LNB     960000u    // f32 [3][128]
#define OFF_BSC     961536u    // f32 [2][128]
#define OFF_BBI     962560u    // f32 [2][128]
#define OFF_USAGE   963584u    // f32 [8]
#define OFF_W8      963712u    // f32 [32768][8]
#define OFF_W1T     2012288u   // f32 [257][128]
#define OFF_GW1HF   2143872u   // bf16 frag [8][8][64][8]
#define OFF_GW1LF   2209408u
#define OFF_CNT     2274944u   // int
#define OFF_LIST    2275008u   // int [32768]

#define DELTA 3e-4f

__device__ __forceinline__ unsigned short f2bf(float f) {
  union { float f; unsigned u; } v; v.f = f;
  return (unsigned short)((v.u + 0x7fffu + ((v.u >> 16) & 1u)) >> 16);
}
__device__ __forceinline__ float bf2f(unsigned short b) {
  union { unsigned u; float f; } v; v.u = ((unsigned)b) << 16; return v.f;
}
__device__ __forceinline__ float frcp(float x) { return __builtin_amdgcn_rcpf(x); }
__device__ __forceinline__ float ftanh(float x) {          // moe epilogue
  float ax = fabsf(x);
  float t = __expf(-2.f * ax);
  float r = (1.f - t) * frcp(1.f + t);
  return copysignf(r, x);
}
__device__ __forceinline__ float ftanh_acc(float x) {      // gate fast path
  float ax = fabsf(x);
  float t = __expf(-2.f * ax);
  float r = (1.f - t) / (1.f + t);
  return copysignf(r, x);
}
__device__ __forceinline__ float fsilu(float x) {
  return x * frcp(1.f + __expf(-x));
}
__device__ __forceinline__ float fgelu(float x) {
  float ax = fabsf(x) * 0.70710678118654752f;
  float t = frcp(fmaf(0.3275911f, ax, 1.f));
  float p = fmaf(t, 1.061405429f, -1.453152027f);
  p = fmaf(t, p, 1.421413741f);
  p = fmaf(t, p, -0.284496736f);
  p = fmaf(t, p, 0.254829592f);
  p *= t;
  float erfv = copysignf(fmaf(-p, __expf(-ax * ax), 1.f), x);
  return 0.5f * x * (1.f + erfv);
}

// ============== prep ==============
__global__ __launch_bounds__(256) void prep_kernel(
    const float* __restrict__ A_W1, const float* __restrict__ A_b1,
    const float* __restrict__ A_W2, const float* __restrict__ A_b2,
    const float* __restrict__ B_W1, const float* __restrict__ B_b1,
    const float* __restrict__ B_g,  const float* __restrict__ B_be,
    const float* __restrict__ B_W2, const float* __restrict__ B_b2,
    const float* __restrict__ C_cw, const float* __restrict__ C_cb,
    const float* __restrict__ C_W,  const float* __restrict__ C_b,
    const float* __restrict__ D_W1, const float* __restrict__ D_b1,
    const float* __restrict__ D_g,  const float* __restrict__ D_be,
    const float* __restrict__ D_W2, const float* __restrict__ D_b2,
    const float* __restrict__ S_W1, const float* __restrict__ S_b1,
    const float* __restrict__ S_g,  const float* __restrict__ S_be,
    const float* __restrict__ S_W2, const float* __restrict__ S_b2,
    const float* __restrict__ G_W1,
    unsigned short* __restrict__ W1cat, unsigned short* __restrict__ W2cat,
    float* __restrict__ W1T,
    unsigned short* __restrict__ GW1HF, unsigned short* __restrict__ GW1LF,
    float* __restrict__ b1cat, float* __restrict__ b2cat,
    float* __restrict__ lng, float* __restrict__ lnb,
    float* __restrict__ bsc, float* __restrict__ bbi,
    float* __restrict__ usage)
{
  int tid = blockIdx.x * 256 + threadIdx.x;
  if (tid < 294912) {                       // W1cat, fragment order
    int g = tid >> 15, rem = tid & 32767;
    int j = rem & 7, lane = (rem >> 3) & 63, nt = (rem >> 9) & 7, ks = rem >> 12;
    int p = nt * 16 + (lane & 15);
    int k = ks * 32 + (lane >> 4) * 8 + j;
    int src = p * 256 + k;
    float v;
    if (g < 2)      v = A_W1[g * 32768 + src];
    else if (g < 4) v = B_W1[(g - 2) * 32768 + src];
    else if (g < 6) {
      int e = g - 4;
      v = 0.f;
      for (int c = 0; c < 4; ++c)
        for (int jj = 0; jj < 3; ++jj) {
          int h = k + 1 - jj;
          if (h >= 0 && h < 256)
            v += C_cw[e*12 + c*3 + jj] * C_W[e*131072 + p*1024 + c*256 + h];
        }
    }
    else if (g < 8) v = D_W1[(g - 6) * 32768 + src];
    else            v = S_W1[src];
    W1cat[tid] = f2bf(v);
    return;
  }
  tid -= 294912;
  if (tid < 114688) {                       // W2cat, fragment order
    int g = tid >> 14, rem = tid & 16383;
    int j = rem & 7, lane = (rem >> 3) & 63, nt = (rem >> 9) & 7, ks = rem >> 12;
    int p = nt * 16 + (lane & 15);
    int k = ks * 32 + (lane >> 4) * 8 + j;
    int src = p * 128 + k;
    float v;
    if (g < 2)      v = A_W2[g * 16384 + src];
    else if (g < 4) v = B_W2[(g - 2) * 16384 + src];
    else if (g < 6) v = D_W2[(g - 4) * 16384 + src];
    else            v = S_W2[src];
    W2cat[tid] = f2bf(v);
    return;
  }
  tid -= 114688;
  if (tid < 32896) {                        // W1T[k][o] = G_W1[o][k]
    int k = tid / 128, o = tid % 128;
    W1T[tid] = G_W1[o * 257 + k];
    return;
  }
  tid -= 32896;
  if (tid < 32768) {                        // gate W1 hi/lo, fragment order
    int j = tid & 7, lane = (tid >> 3) & 63, nt = (tid >> 9) & 7, ks = tid >> 12;
    int o = nt * 16 + (lane & 15);
    int k = ks * 32 + (lane >> 4) * 8 + j;
    float v = G_W1[o * 257 + k];
    unsigned short h = f2bf(v);
    GW1HF[tid] = h;
    GW1LF[tid] = f2bf(v - bf2f(h));
    return;
  }
  tid -= 32768;
  if (tid < 1152) {                         // b1cat (C fold added by prep2)
    int g = tid / 128, p = tid % 128;
    float v;
    if (g < 2)      v = A_b1[tid];
    else if (g < 4) v = B_b1[p + (g - 2) * 128];
    else if (g < 6) v = C_b[(g - 4) * 128 + p];
    else if (g < 8) v = D_b1[p + (g - 6) * 128];
    else            v = S_b1[p];
    b1cat[tid] = v;
    return;
  }
  tid -= 1152;
  if (tid < 896) {                          // b2cat
    int g = tid / 128, p = tid % 128;
    float v;
    if (g < 2)      v = A_b2[tid];
    else if (g < 4) v = B_b2[p + (g - 2) * 128];
    else if (g < 6) v = D_b2[p + (g - 4) * 128];
    else            v = S_b2[p];
    b2cat[tid] = v;
    return;
  }
  tid -= 896;
  if (tid < 768) {
    if (tid < 384) {
      int j = tid / 128, p = tid % 128;
      lng[tid] = (j < 2) ? D_g[tid] : S_g[p];
    } else {
      int q = tid - 384; int j = q / 128, p = q % 128;
      lnb[q] = (j < 2) ? D_be[q] : S_be[p];
    }
    return;
  }
  tid -= 768;
  if (tid < 512) {
    if (tid < 256) bsc[tid] = B_g[tid];
    else           bbi[tid - 256] = B_be[tid - 256];
    return;
  }
  tid -= 512;
  if (tid < 8) usage[tid] = 0.f;
}

// prep2: conv-bias fold + counter zero
__global__ __launch_bounds__(256) void prep2_kernel(
    const float* __restrict__ C_cw_unused, const float* __restrict__ C_cb,
    const float* __restrict__ C_W, float* __restrict__ b1cat, int* __restrict__ cnt)
{
  int tid = blockIdx.x * 256 + threadIdx.x;
  if (tid == 0) *cnt = 0;
  int e = tid >> 9, rem = tid & 511;
  int p = rem >> 2, c = rem & 3;
  const float4* row = (const float4*)(C_W + e*131072 + p*1024 + c*256);
  float s = 0.f;
  for (int q = 0; q < 64; ++q) {
    float4 v = row[q];
    s += v.x + v.y + v.z + v.w;
  }
  atomicAdd(&b1cat[(4 + e) * 128 + p], C_cb[e * 4 + c] * s);
}

// ============== gate_fast: MFMA bf16x3, o-half split, flag compaction ==============
__global__ __launch_bounds__(512, 4) void gate_fast_kernel(
    const float* __restrict__ x, const int* __restrict__ modality,
    const unsigned short* __restrict__ GW1HF, const unsigned short* __restrict__ GW1LF,
    const float* __restrict__ G_W1, const float* __restrict__ G_b1,
    const float* __restrict__ G_W2, const float* __restrict__ G_b2,
    float* __restrict__ w8full, float* __restrict__ usage,
    int* __restrict__ cnt, int* __restrict__ list)
{
  __shared__ float gh[64][132];
  __shared__ float lgs[64][9];
  const int tid = threadIdx.x;
  const int wv = tid >> 6, lane = tid & 63;
  const int l15 = lane & 15, l4 = lane >> 4;
  const int tg = wv >> 1, half = wv & 1;
  const int tb = blockIdx.x * 64;
  const int tw = tb + tg * 16;

  const short8* srcH = (const short8*)GW1HF;
  const short8* srcL = (const short8*)GW1LF;

  short8 XH[8], XL[8];
#pragma unroll
  for (int ks = 0; ks < 8; ++ks) {
    const float* xr = x + (size_t)(tw + l15) * 256 + ks * 32 + l4 * 8;
    float4 u = *(const float4*)xr, v = *(const float4*)(xr + 4);
    float xv[8] = {u.x, u.y, u.z, u.w, v.x, v.y, v.z, v.w};
    short8 hh, ll;
#pragma unroll
    for (int j2 = 0; j2 < 8; ++j2) {
      unsigned short h = f2bf(xv[j2]);
      hh[j2] = (short)h;
      ll[j2] = (short)f2bf(xv[j2] - bf2f(h));
    }
    XH[ks] = hh; XL[ks] = ll;
  }

  f32x4 zero = {0.f, 0.f, 0.f, 0.f};
  f32x4 acc[4];
#pragma unroll
  for (int n = 0; n < 4; ++n) acc[n] = zero;
#pragma unroll
  for (int ks = 0; ks < 8; ++ks) {
#pragma unroll
    for (int n = 0; n < 4; ++n) {
      int fi = ks * 512 + (half * 4 + n) * 64 + lane;
      short8 bh = srcH[fi];
      short8 bl = srcL[fi];
      acc[n] = MFMA16(XH[ks], bh, acc[n]);
      acc[n] = MFMA16(XH[ks], bl, acc[n]);
      acc[n] = MFMA16(XL[ks], bh, acc[n]);
    }
  }
  float mf[4];
#pragma unroll
  for (int r = 0; r < 4; ++r) mf[r] = (float)modality[tw + l4 * 4 + r];
#pragma unroll
  for (int n = 0; n < 4; ++n) {
    int o = (half * 4 + n) * 16 + l15;
    float wm = G_W1[o * 257 + 256];
    float b = G_b1[o];
#pragma unroll
    for (int r = 0; r < 4; ++r)
      gh[tg * 16 + l4 * 4 + r][o] = ftanh_acc(fmaf(mf[r], wm, acc[n][r]) + b);
  }
  __syncthreads();

  {                                         // layer 2: thread = (token, expert)
    int t2 = tid >> 3, e2 = tid & 7;
    float lg = 0.f;
    for (int o2 = 0; o2 < 128; ++o2)
      lg = fmaf(gh[t2][o2], G_W2[e2 * 128 + o2], lg);
    float s = (lg + G_b2[e2]) / 0.7f;
    lgs[t2][e2] = fminf(fmaxf(s, -10.f), 10.f);
  }
  __syncthreads();

  if (wv == 0) {                            // 64 tokens on 64 lanes
    int token = tb + lane;
    float v[8];
#pragma unroll
    for (int e = 0; e < 8; ++e) v[e] = lgs[lane][e];
    float tv[5]; int ti[5]; unsigned msk = 0;
    for (int kk = 0; kk < 5; ++kk) {
      float best = -1e30f; int bi = 0;
      for (int e = 0; e < 8; ++e)
        if (!((msk >> e) & 1u) && v[e] > best) { best = v[e]; bi = e; }
      tv[kk] = best; ti[kk] = bi; msk |= 1u << bi;
    }
    float uw[8];
#pragma unroll
    for (int e = 0; e < 8; ++e) uw[e] = 0.f;
    if (tv[3] - tv[4] < DELTA) {            // near-tie -> np-exact recompute later
      int idx = atomicAdd(cnt, 1);
      list[idx] = token;
    } else {
      float mx = tv[0], den = 0.f, wk4[4];
#pragma unroll
      for (int kk = 0; kk < 4; ++kk) { wk4[kk] = expf(tv[kk] - mx); den += wk4[kk]; }
#pragma unroll
      for (int e = 0; e < 8; ++e) {
        float val = 0.f;
#pragma unroll
        for (int kk = 0; kk < 4; ++kk) if (ti[kk] == e) val = wk4[kk] / den;
        w8full[(size_t)token * 8 + e] = val;
      }
      float dall = 0.f, pe[8];
#pragma unroll
      for (int e = 0; e < 8; ++e) { pe[e] = expf(v[e] - mx); dall += pe[e]; }
#pragma unroll
      for (int e = 0; e < 8; ++e) uw[e] = pe[e] / dall;
    }
    for (int m = 1; m <= 32; m <<= 1)
#pragma unroll
      for (int e = 0; e < 8; ++e) uw[e] += __shfl_xor(uw[e], m);
    if (lane == 0)
      for (int e = 0; e < 8; ++e) atomicAdd(usage + e, uw[e]);
  }
}

// ============== gate_slow v3: LDS W1T + 2 tokens/wave (4-chain ILP) ==============
// Per (t,o) arithmetic bit-identical to round-12 oracle. 8 tokens per block lap.
__global__ __launch_bounds__(256) void gate_slow_kernel(
    const float* __restrict__ x, const int* __restrict__ modality,
    const float* __restrict__ W1T, const float* __restrict__ G_b1,
    const float* __restrict__ G_W2, const float* __restrict__ G_b2,
    const int* __restrict__ cnt, const int* __restrict__ list,
    float* __restrict__ w8full, float* __restrict__ usage)
{
  __shared__ float w1l[32896];              // [257][128] f32
  __shared__ float w2l[8][132];
  __shared__ float xs[4][2][256];
  __shared__ float gh[4][2][128];
  const int n = *cnt;
  if (blockIdx.x * 8 >= n) return;          // no tokens for this block

  for (int idx = threadIdx.x; idx < 8224; idx += 256)
    ((float4*)w1l)[idx] = ((const float4*)W1T)[idx];
  for (int idx = threadIdx.x; idx < 1024; idx += 256)
    w2l[idx >> 7][idx & 127] = G_W2[idx];
  __syncthreads();

  const int wvl = threadIdx.x >> 6, lane = threadIdx.x & 63;
  for (int i0 = blockIdx.x * 8 + wvl * 2; i0 < n; i0 += 2048) {
    const bool v1 = (i0 + 1) < n;
    const int T0 = __builtin_amdgcn_readfirstlane(list[i0]);
    const int T1 = __builtin_amdgcn_readfirstlane(v1 ? list[i0 + 1] : list[i0]);
#pragma unroll
    for (int q = 0; q < 4; ++q) {
      xs[wvl][0][q * 64 + lane] = x[(size_t)T0 * 256 + q * 64 + lane];
      xs[wvl][1][q * 64 + lane] = x[(size_t)T1 * 256 + q * 64 + lane];
    }
    float a0 = 0.f, a1 = 0.f, c0 = 0.f, c1 = 0.f;
#pragma unroll 8
    for (int k = 0; k < 256; ++k) {         // exact sequential-k chains (np order)
      float w0 = w1l[k * 128 + lane];
      float w1 = w1l[k * 128 + 64 + lane];
      float x0 = xs[wvl][0][k];
      float x1 = xs[wvl][1][k];
      a0 = fmaf(x0, w0, a0);
      a1 = fmaf(x0, w1, a1);
      c0 = fmaf(x1, w0, c0);
      c1 = fmaf(x1, w1, c1);
    }
    {
      float xm0 = (float)modality[T0];
      float xm1 = (float)modality[T1];
      float w0 = w1l[256 * 128 + lane];
      float w1 = w1l[256 * 128 + 64 + lane];
      a0 = fmaf(xm0, w0, a0);
      a1 = fmaf(xm0, w1, a1);
      c0 = fmaf(xm1, w0, c0);
      c1 = fmaf(xm1, w1, c1);
    }
    gh[wvl][0][lane]      = (float)tanh((double)(a0 + G_b1[lane]));
    gh[wvl][0][64 + lane] = (float)tanh((double)(a1 + G_b1[64 + lane]));
    gh[wvl][1][lane]      = (float)tanh((double)(c0 + G_b1[lane]));
    gh[wvl][1][64 + lane] = (float)tanh((double)(c1 + G_b1[64 + lane]));
    float lg = 0.f;
    if (lane < 16) {
      int tt2 = lane >> 3, ee = lane & 7;
      for (int o = 0; o < 128; ++o)         // exact sequential-o chain
        lg = fmaf(gh[wvl][tt2][o], w2l[ee][o], lg);
    }
    // lane 0 finalizes T0; lane 8 finalizes T1 (if valid)
    float v[8];
#pragma unroll
    for (int e = 0; e < 8; ++e) v[e] = __shfl(lg, (lane & 8) + e);
    if (lane == 0 || (lane == 8 && v1)) {
      const int T = (lane == 0) ? T0 : T1;
#pragma unroll
      for (int e = 0; e < 8; ++e)
        v[e] = fminf(fmaxf((v[e] + G_b2[e]) / 0.7f, -10.f), 10.f);
      float tv[4]; int ti[4]; unsigned msk = 0;
      for (int kk = 0; kk < 4; ++kk) {
        float best = -1e30f; int bi = 0;
        for (int e = 0; e < 8; ++e)
          if (!((msk >> e) & 1u) && v[e] > best) { best = v[e]; bi = e; }
        tv[kk] = best; ti[kk] = bi; msk |= 1u << bi;
      }
      float mx = tv[0], den = 0.f, wk4[4];
#pragma unroll
      for (int kk = 0; kk < 4; ++kk) { wk4[kk] = expf(tv[kk] - mx); den += wk4[kk]; }
#pragma unroll
      for (int e = 0; e < 8; ++e) {
        float val = 0.f;
#pragma unroll
        for (int kk = 0; kk < 4; ++kk) if (ti[kk] == e) val = wk4[kk] / den;
        w8full[(size_t)T * 8 + e] = val;
      }
      float dall = 0.f, pe[8];
#pragma unroll
      for (int e = 0; e < 8; ++e) { pe[e] = expf(v[e] - mx); dall += pe[e]; }
      for (int e = 0; e < 8; ++e) atomicAdd(usage + e, pe[e] / dall);
    }
  }
}

// ============== moe v10 (round-12, unchanged) ==============
__global__ __launch_bounds__(512, 2) void moe_kernel(
    const float* __restrict__ x,
    const unsigned short* __restrict__ W1cat, const unsigned short* __restrict__ W2cat,
    const float* __restrict__ b1cat, const float* __restrict__ b2cat,
    const float* __restrict__ lng, const float* __restrict__ lnb,
    const float* __restrict__ bsc, const float* __restrict__ bbi,
    const float* __restrict__ w8full, float* __restrict__ out)
{
  __shared__ unsigned char smem[131072];    // W1L 64K | W2L 32K | HS 8x4K
  short8* W1L = (short8*)smem;
  short8* W2L = (short8*)(smem + 65536);
  unsigned char* HS = smem + 98304 + (threadIdx.x >> 6) * 4096;

  const int tid = threadIdx.x;
  const int wv = tid >> 6, lane = tid & 63;
  const int l15 = lane & 15, l4 = lane >> 4;
  const int tb = blockIdx.x * 128 + wv * 16;
  const short8* W1f = (const short8*)W1cat;
  const short8* W2f = (const short8*)W2cat;

  short8 A[8];
#pragma unroll
  for (int ks = 0; ks < 8; ++ks) {
    const float* xr = x + (size_t)(tb + l15) * 256 + ks * 32 + l4 * 8;
    float4 u = *(const float4*)xr, v = *(const float4*)(xr + 4);
    short8 a;
    a[0]=(short)f2bf(u.x); a[1]=(short)f2bf(u.y); a[2]=(short)f2bf(u.z); a[3]=(short)f2bf(u.w);
    a[4]=(short)f2bf(v.x); a[5]=(short)f2bf(v.y); a[6]=(short)f2bf(v.z); a[7]=(short)f2bf(v.w);
    A[ks] = a;
  }

  f32x4 zero = {0.f, 0.f, 0.f, 0.f};
  f32x4 pacc[8];
#pragma unroll
  for (int nt = 0; nt < 8; ++nt) pacc[nt] = zero;
  const float RS = 1.0f / sqrtf(1.0f + 1e-5f);

  short8 stg[12];
#pragma unroll
  for (int i = 0; i < 8; ++i) stg[i] = W1f[tid + i * 512];
#pragma unroll
  for (int i = 0; i < 4; ++i) stg[8 + i] = W2f[tid + i * 512];

  for (int g = 0; g < 9; ++g) {
    const int type = (g < 2) ? 0 : (g < 4) ? 1 : (g < 6) ? 2 : (g < 8) ? 3 : 4;
    const int g2 = (g < 4) ? g : ((g == 8) ? 6 : g - 2);

    __syncthreads();
#pragma unroll
    for (int i = 0; i < 8; ++i) W1L[tid + i * 512] = stg[i];
#pragma unroll
    for (int i = 0; i < 4; ++i) W2L[tid + i * 512] = stg[8 + i];
    if (g < 8) {
      int gn = g + 1;
      int g2n = (gn < 4) ? gn : ((gn == 8) ? 6 : gn - 2);
#pragma unroll
      for (int i = 0; i < 8; ++i) stg[i] = W1f[(size_t)gn * 4096 + tid + i * 512];
#pragma unroll
      for (int i = 0; i < 4; ++i) stg[8 + i] = W2f[(size_t)g2n * 2048 + tid + i * 512];
    }
    __syncthreads();

    f32x4 acc[8];
#pragma unroll
    for (int nt = 0; nt < 8; ++nt) acc[nt] = zero;
#pragma unroll
    for (int ks = 0; ks < 8; ++ks)
#pragma unroll
      for (int nt = 0; nt < 8; ++nt)
        acc[nt] = MFMA16(A[ks], W1L[(ks * 8 + nt) * 64 + lane], acc[nt]);

    const float* b1 = b1cat + g * 128;

    if (type == 2) {
#pragma unroll
      for (int r = 0; r < 4; ++r) {
        float wv_ = w8full[(size_t)(tb + l4 * 4 + r) * 8 + g];
#pragma unroll
        for (int nt = 0; nt < 8; ++nt) {
          float h = fgelu(acc[nt][r] + b1[nt * 16 + l15]);
          pacc[nt][r] += wv_ * h;
        }
      }
      continue;
    }
#pragma unroll
    for (int r = 0; r < 4; ++r)
#pragma unroll
      for (int nt = 0; nt < 8; ++nt) {
        float h = acc[nt][r] + b1[nt * 16 + l15];
        if (type == 0)      h = fmaxf(h, 0.f);
        else if (type == 1) {
          int col = (g - 2) * 128 + nt * 16 + l15;
          h = ftanh(h) * RS * bsc[col] + bbi[col];
        }
        else if (type == 3) h = fsilu(h);
        else                h = fmaxf(h, 0.f);
        acc[nt][r] = h;
      }
    if (type >= 3) {
      int li = (type == 4) ? 2 : (g - 6);
#pragma unroll
      for (int r = 0; r < 4; ++r) {
        float s1 = 0.f, s2 = 0.f;
#pragma unroll
        for (int nt = 0; nt < 8; ++nt) { float h = acc[nt][r]; s1 += h; s2 += h * h; }
        for (int m = 1; m <= 8; m <<= 1) { s1 += __shfl_xor(s1, m); s2 += __shfl_xor(s2, m); }
        float mu = s1 * (1.f / 128.f);
        float var = s2 * (1.f / 128.f) - mu * mu;
        float sc = __builtin_amdgcn_rsqf(var + 1e-5f);
#pragma unroll
        for (int nt = 0; nt < 8; ++nt) {
          int col = nt * 16 + l15;
          acc[nt][r] = (acc[nt][r] - mu) * sc * lng[li * 128 + col] + lnb[li * 128 + col];
        }
      }
    }
#pragma unroll
    for (int r = 0; r < 4; ++r) {
      int row = l4 * 4 + r;
#pragma unroll
      for (int nt = 0; nt < 8; ++nt) {
        int bytecol = (nt * 16 + l15) * 2;
        int addr = row * 256 + ((((bytecol >> 4) ^ (row & 7)) << 4) | (bytecol & 15));
        *(unsigned short*)(HS + addr) = f2bf(acc[nt][r]);
      }
    }
    short8 a2[4];
#pragma unroll
    for (int ks = 0; ks < 4; ++ks) {
      int ar = l15 * 256 + ((((ks * 4 + l4) ^ (l15 & 7)) << 4));
      a2[ks] = *(const short8*)(HS + ar);
    }
    f32x4 acc2[8];
#pragma unroll
    for (int nt = 0; nt < 8; ++nt) acc2[nt] = zero;
#pragma unroll
    for (int ks = 0; ks < 4; ++ks)
#pragma unroll
      for (int nt = 0; nt < 8; ++nt)
        acc2[nt] = MFMA16(a2[ks], W2L[(ks * 8 + nt) * 64 + lane], acc2[nt]);

    const float* b2 = b2cat + g2 * 128;
    if (type == 4) {
#pragma unroll
      for (int r = 0; r < 4; ++r) {
        int token = tb + l4 * 4 + r;
#pragma unroll
        for (int nt = 0; nt < 8; ++nt)
          out[(size_t)token * 128 + nt * 16 + l15] = acc2[nt][r] + b2[nt * 16 + l15];
      }
    } else {
#pragma unroll
      for (int r = 0; r < 4; ++r) {
        float wv_ = w8full[(size_t)(tb + l4 * 4 + r) * 8 + g];
#pragma unroll
        for (int nt = 0; nt < 8; ++nt)
          pacc[nt][r] += wv_ * (acc2[nt][r] + b2[nt * 16 + l15]);
      }
    }
  }
#pragma unroll
  for (int r = 0; r < 4; ++r) {
    int token = tb + l4 * 4 + r;
#pragma unroll
    for (int nt = 0; nt < 8; ++nt)
      out[4194304 + (size_t)token * 128 + nt * 16 + l15] = pacc[nt][r];
  }
}

// ============== aux scalar ==============
__global__ void aux_kernel(const float* __restrict__ usage, float* __restrict__ out) {
  if (threadIdx.x == 0 && blockIdx.x == 0) {
    float a = 0.f;
    for (int e = 0; e < 8; ++e) {
      float u = usage[e] * (1.0f / 32768.0f);
      a += 0.125f * (logf(0.125f) - logf(u + 1e-10f));
    }
    out[8388608] = a * 0.125f;
  }
}

extern "C" void kernel_launch(void* const* d_in, const int* in_sizes, int n_in,
                              void* d_out, int out_size, void* d_ws, size_t ws_size,
                              hipStream_t stream) {
  (void)in_sizes; (void)n_in; (void)out_size; (void)ws_size;
  const float* x    = (const float*)d_in[0];
  const int*   mod  = (const int*)d_in[1];
  const float* A_W1 = (const float*)d_in[2];
  const float* A_b1 = (const float*)d_in[3];
  const float* A_W2 = (const float*)d_in[4];
  const float* A_b2 = (const float*)d_in[5];
  const float* B_W1 = (const float*)d_in[6];
  const float* B_b1 = (const float*)d_in[7];
  const float* B_g  = (const float*)d_in[8];
  const float* B_be = (const float*)d_in[9];
  const float* B_W2 = (const float*)d_in[10];
  const float* B_b2 = (const float*)d_in[11];
  const float* C_cw = (const float*)d_in[12];
  const float* C_cb = (const float*)d_in[13];
  const float* C_W  = (const float*)d_in[14];
  const float* C_b  = (const float*)d_in[15];
  const float* D_W1 = (const float*)d_in[16];
  const float* D_b1 = (const float*)d_in[17];
  const float* D_g  = (const float*)d_in[18];
  const float* D_be = (const float*)d_in[19];
  const float* D_W2 = (const float*)d_in[20];
  const float* D_b2 = (const float*)d_in[21];
  const float* S_W1 = (const float*)d_in[22];
  const float* S_b1 = (const float*)d_in[23];
  const float* S_g  = (const float*)d_in[24];
  const float* S_be = (const float*)d_in[25];
  const float* S_W2 = (const float*)d_in[26];
  const float* S_b2 = (const float*)d_in[27];
  const float* G_W1 = (const float*)d_in[28];
  const float* G_b1 = (const float*)d_in[29];
  const float* G_W2 = (const float*)d_in[30];
  const float* G_b2 = (const float*)d_in[31];

  char* ws = (char*)d_ws;
  unsigned short* W1cat = (unsigned short*)(ws + OFF_W1CAT);
  unsigned short* W2cat = (unsigned short*)(ws + OFF_W2CAT);
  float* W1T    = (float*)(ws + OFF_W1T);
  unsigned short* GW1HF = (unsigned short*)(ws + OFF_GW1HF);
  unsigned short* GW1LF = (unsigned short*)(ws + OFF_GW1LF);
  float* b1cat  = (float*)(ws + OFF_B1);
  float* b2cat  = (float*)(ws + OFF_B2);
  float* lng    = (float*)(ws + OFF_LNG);
  float* lnb    = (float*)(ws + OFF_LNB);
  float* bsc    = (float*)(ws + OFF_BSC);
  float* bbi    = (float*)(ws + OFF_BBI);
  float* usage  = (float*)(ws + OFF_USAGE);
  float* w8full = (float*)(ws + OFF_W8);
  int*   cnt    = (int*)(ws + OFF_CNT);
  int*   list   = (int*)(ws + OFF_LIST);
  float* out    = (float*)d_out;

  prep_kernel<<<1870, 256, 0, stream>>>(A_W1, A_b1, A_W2, A_b2, B_W1, B_b1, B_g, B_be,
      B_W2, B_b2, C_cw, C_cb, C_W, C_b, D_W1, D_b1, D_g, D_be, D_W2, D_b2,
      S_W1, S_b1, S_g, S_be, S_W2, S_b2, G_W1,
      W1cat, W2cat, W1T, GW1HF, GW1LF, b1cat, b2cat, lng, lnb, bsc, bbi, usage);
  prep2_kernel<<<4, 256, 0, stream>>>(C_cw, C_cb, C_W, b1cat, cnt);
  gate_fast_kernel<<<512, 512, 0, stream>>>(x, mod, GW1HF, GW1LF, G_W1, G_b1,
      G_W2, G_b2, w8full, usage, cnt, list);
  gate_slow_kernel<<<256, 256, 0, stream>>>(x, mod, W1T, G_b1, G_W2, G_b2,
      cnt, list, w8full, usage);
  moe_kernel<<<256, 512, 0, stream>>>(x, W1cat, W2cat, b1cat, b2cat, lng, lnb,
      bsc, bbi, w8full, out);
  aux_kernel<<<1, 64, 0, stream>>>(usage, out);
}

// Round 17
// 214.011 us; speedup vs baseline: 2.5290x; 1.1084x over previous
//
#include <hip/hip_runtime.h>
#include <hip/hip_bf16.h>
#include <math.h>

typedef __attribute__((ext_vector_type(8))) short short8;      // 8 bf16 (4 VGPRs)
typedef __attribute__((ext_vector_type(4))) float f32x4;       // MFMA acc
typedef __attribute__((ext_vector_type(4))) unsigned short us4;

#define MFMA16(a,b,c) __builtin_amdgcn_mfma_f32_16x16x32_bf16((a),(b),(c),0,0,0)

// ---------------- workspace layout (bytes) ----------------
#define OFF_W1CAT   0u         // bf16 frag [9][8][8][64][8]
#define OFF_W2CAT   589824u    // bf16 frag [7][4][8][64][8]
#define OFF_B1      950272u    // f32 [9][128]
#define OFF_B2      954880u    // f32 [7][128]
#define OFF_LNG     958464u    // f32 [3][128]
#define OFF_LNB     960000u    // f32 [3][128]
#define OFF_BSC     961536u    // f32 [2][128]
#define OFF_BBI     962560u    // f32 [2][128]
#define OFF_USAGE   963584u    // f32 [8]
#define OFF_W8      963712u    // f32 [32768][8]
#define OFF_W1T     2012288u   // f32 [257][128]
#define OFF_GW1HF   2143872u   // bf16 frag [8][8][64][8]
#define OFF_GW1LF   2209408u
#define OFF_CNT     2274944u   // int
#define OFF_LIST    2275008u   // int [32768]

#define DELTA 3e-4f

__device__ __forceinline__ unsigned short f2bf(float f) {
  union { float f; unsigned u; } v; v.f = f;
  return (unsigned short)((v.u + 0x7fffu + ((v.u >> 16) & 1u)) >> 16);
}
__device__ __forceinline__ float bf2f(unsigned short b) {
  union { unsigned u; float f; } v; v.u = ((unsigned)b) << 16; return v.f;
}
__device__ __forceinline__ float frcp(float x) { return __builtin_amdgcn_rcpf(x); }
__device__ __forceinline__ float ftanh(float x) {          // moe epilogue
  float ax = fabsf(x);
  float t = __expf(-2.f * ax);
  float r = (1.f - t) * frcp(1.f + t);
  return copysignf(r, x);
}
__device__ __forceinline__ float ftanh_acc(float x) {      // gate fast path
  float ax = fabsf(x);
  float t = __expf(-2.f * ax);
  float r = (1.f - t) / (1.f + t);
  return copysignf(r, x);
}
__device__ __forceinline__ float fsilu(float x) {
  return x * frcp(1.f + __expf(-x));
}
__device__ __forceinline__ float fgelu(float x) {
  float ax = fabsf(x) * 0.70710678118654752f;
  float t = frcp(fmaf(0.3275911f, ax, 1.f));
  float p = fmaf(t, 1.061405429f, -1.453152027f);
  p = fmaf(t, p, 1.421413741f);
  p = fmaf(t, p, -0.284496736f);
  p = fmaf(t, p, 0.254829592f);
  p *= t;
  float erfv = copysignf(fmaf(-p, __expf(-ax * ax), 1.f), x);
  return 0.5f * x * (1.f + erfv);
}
// async global->LDS DMA, 16B per lane; lds dest = wave-uniform base + lane*16
__device__ __forceinline__ void gld_lds16(const void* g, void* l) {
  __builtin_amdgcn_global_load_lds(
      (const __attribute__((address_space(1))) void*)g,
      (__attribute__((address_space(3))) void*)l, 16, 0, 0);
}

// ============== prep ==============
__global__ __launch_bounds__(256) void prep_kernel(
    const float* __restrict__ A_W1, const float* __restrict__ A_b1,
    const float* __restrict__ A_W2, const float* __restrict__ A_b2,
    const float* __restrict__ B_W1, const float* __restrict__ B_b1,
    const float* __restrict__ B_g,  const float* __restrict__ B_be,
    const float* __restrict__ B_W2, const float* __restrict__ B_b2,
    const float* __restrict__ C_cw, const float* __restrict__ C_cb,
    const float* __restrict__ C_W,  const float* __restrict__ C_b,
    const float* __restrict__ D_W1, const float* __restrict__ D_b1,
    const float* __restrict__ D_g,  const float* __restrict__ D_be,
    const float* __restrict__ D_W2, const float* __restrict__ D_b2,
    const float* __restrict__ S_W1, const float* __restrict__ S_b1,
    const float* __restrict__ S_g,  const float* __restrict__ S_be,
    const float* __restrict__ S_W2, const float* __restrict__ S_b2,
    const float* __restrict__ G_W1,
    unsigned short* __restrict__ W1cat, unsigned short* __restrict__ W2cat,
    float* __restrict__ W1T,
    unsigned short* __restrict__ GW1HF, unsigned short* __restrict__ GW1LF,
    float* __restrict__ b1cat, float* __restrict__ b2cat,
    float* __restrict__ lng, float* __restrict__ lnb,
    float* __restrict__ bsc, float* __restrict__ bbi,
    float* __restrict__ usage)
{
  int tid = blockIdx.x * 256 + threadIdx.x;
  if (tid < 294912) {                       // W1cat, fragment order
    int g = tid >> 15, rem = tid & 32767;
    int j = rem & 7, lane = (rem >> 3) & 63, nt = (rem >> 9) & 7, ks = rem >> 12;
    int p = nt * 16 + (lane & 15);
    int k = ks * 32 + (lane >> 4) * 8 + j;
    int src = p * 256 + k;
    float v;
    if (g < 2)      v = A_W1[g * 32768 + src];
    else if (g < 4) v = B_W1[(g - 2) * 32768 + src];
    else if (g < 6) {
      int e = g - 4;
      v = 0.f;
      for (int c = 0; c < 4; ++c)
        for (int jj = 0; jj < 3; ++jj) {
          int h = k + 1 - jj;
          if (h >= 0 && h < 256)
            v += C_cw[e*12 + c*3 + jj] * C_W[e*131072 + p*1024 + c*256 + h];
        }
    }
    else if (g < 8) v = D_W1[(g - 6) * 32768 + src];
    else            v = S_W1[src];
    W1cat[tid] = f2bf(v);
    return;
  }
  tid -= 294912;
  if (tid < 114688) {                       // W2cat, fragment order
    int g = tid >> 14, rem = tid & 16383;
    int j = rem & 7, lane = (rem >> 3) & 63, nt = (rem >> 9) & 7, ks = rem >> 12;
    int p = nt * 16 + (lane & 15);
    int k = ks * 32 + (lane >> 4) * 8 + j;
    int src = p * 128 + k;
    float v;
    if (g < 2)      v = A_W2[g * 16384 + src];
    else if (g < 4) v = B_W2[(g - 2) * 16384 + src];
    else if (g < 6) v = D_W2[(g - 4) * 16384 + src];
    else            v = S_W2[src];
    W2cat[tid] = f2bf(v);
    return;
  }
  tid -= 114688;
  if (tid < 32896) {                        // W1T[k][o] = G_W1[o][k]
    int k = tid / 128, o = tid % 128;
    W1T[tid] = G_W1[o * 257 + k];
    return;
  }
  tid -= 32896;
  if (tid < 32768) {                        // gate W1 hi/lo, fragment order
    int j = tid & 7, lane = (tid >> 3) & 63, nt = (tid >> 9) & 7, ks = tid >> 12;
    int o = nt * 16 + (lane & 15);
    int k = ks * 32 + (lane >> 4) * 8 + j;
    float v = G_W1[o * 257 + k];
    unsigned short h = f2bf(v);
    GW1HF[tid] = h;
    GW1LF[tid] = f2bf(v - bf2f(h));
    return;
  }
  tid -= 32768;
  if (tid < 1152) {                         // b1cat (C fold added by prep2)
    int g = tid / 128, p = tid % 128;
    float v;
    if (g < 2)      v = A_b1[tid];
    else if (g < 4) v = B_b1[p + (g - 2) * 128];
    else if (g < 6) v = C_b[(g - 4) * 128 + p];
    else if (g < 8) v = D_b1[p + (g - 6) * 128];
    else            v = S_b1[p];
    b1cat[tid] = v;
    return;
  }
  tid -= 1152;
  if (tid < 896) {                          // b2cat
    int g = tid / 128, p = tid % 128;
    float v;
    if (g < 2)      v = A_b2[tid];
    else if (g < 4) v = B_b2[p + (g - 2) * 128];
    else if (g < 6) v = D_b2[p + (g - 4) * 128];
    else            v = S_b2[p];
    b2cat[tid] = v;
    return;
  }
  tid -= 896;
  if (tid < 768) {
    if (tid < 384) {
      int j = tid / 128, p = tid % 128;
      lng[tid] = (j < 2) ? D_g[tid] : S_g[p];
    } else {
      int q = tid - 384; int j = q / 128, p = q % 128;
      lnb[q] = (j < 2) ? D_be[q] : S_be[p];
    }
    return;
  }
  tid -= 768;
  if (tid < 512) {
    if (tid < 256) bsc[tid] = B_g[tid];
    else           bbi[tid - 256] = B_be[tid - 256];
    return;
  }
  tid -= 512;
  if (tid < 8) usage[tid] = 0.f;
}

// prep2: conv-bias fold + counter zero
__global__ __launch_bounds__(256) void prep2_kernel(
    const float* __restrict__ C_cw_unused, const float* __restrict__ C_cb,
    const float* __restrict__ C_W, float* __restrict__ b1cat, int* __restrict__ cnt)
{
  int tid = blockIdx.x * 256 + threadIdx.x;
  if (tid == 0) *cnt = 0;
  int e = tid >> 9, rem = tid & 511;
  int p = rem >> 2, c = rem & 3;
  const float4* row = (const float4*)(C_W + e*131072 + p*1024 + c*256);
  float s = 0.f;
  for (int q = 0; q < 64; ++q) {
    float4 v = row[q];
    s += v.x + v.y + v.z + v.w;
  }
  atomicAdd(&b1cat[(4 + e) * 128 + p], C_cb[e * 4 + c] * s);
}

// ============== gate_fast: MFMA bf16x3, o-half split, flag compaction ==============
__global__ __launch_bounds__(512, 4) void gate_fast_kernel(
    const float* __restrict__ x, const int* __restrict__ modality,
    const unsigned short* __restrict__ GW1HF, const unsigned short* __restrict__ GW1LF,
    const float* __restrict__ G_W1, const float* __restrict__ G_b1,
    const float* __restrict__ G_W2, const float* __restrict__ G_b2,
    float* __restrict__ w8full, float* __restrict__ usage,
    int* __restrict__ cnt, int* __restrict__ list)
{
  __shared__ float gh[64][132];
  __shared__ float lgs[64][9];
  const int tid = threadIdx.x;
  const int wv = tid >> 6, lane = tid & 63;
  const int l15 = lane & 15, l4 = lane >> 4;
  const int tg = wv >> 1, half = wv & 1;
  const int tb = blockIdx.x * 64;
  const int tw = tb + tg * 16;

  const short8* srcH = (const short8*)GW1HF;
  const short8* srcL = (const short8*)GW1LF;

  short8 XH[8], XL[8];
#pragma unroll
  for (int ks = 0; ks < 8; ++ks) {
    const float* xr = x + (size_t)(tw + l15) * 256 + ks * 32 + l4 * 8;
    float4 u = *(const float4*)xr, v = *(const float4*)(xr + 4);
    float xv[8] = {u.x, u.y, u.z, u.w, v.x, v.y, v.z, v.w};
    short8 hh, ll;
#pragma unroll
    for (int j2 = 0; j2 < 8; ++j2) {
      unsigned short h = f2bf(xv[j2]);
      hh[j2] = (short)h;
      ll[j2] = (short)f2bf(xv[j2] - bf2f(h));
    }
    XH[ks] = hh; XL[ks] = ll;
  }

  f32x4 zero = {0.f, 0.f, 0.f, 0.f};
  f32x4 acc[4];
#pragma unroll
  for (int n = 0; n < 4; ++n) acc[n] = zero;
#pragma unroll
  for (int ks = 0; ks < 8; ++ks) {
#pragma unroll
    for (int n = 0; n < 4; ++n) {
      int fi = ks * 512 + (half * 4 + n) * 64 + lane;
      short8 bh = srcH[fi];
      short8 bl = srcL[fi];
      acc[n] = MFMA16(XH[ks], bh, acc[n]);
      acc[n] = MFMA16(XH[ks], bl, acc[n]);
      acc[n] = MFMA16(XL[ks], bh, acc[n]);
    }
  }
  float mf[4];
#pragma unroll
  for (int r = 0; r < 4; ++r) mf[r] = (float)modality[tw + l4 * 4 + r];
#pragma unroll
  for (int n = 0; n < 4; ++n) {
    int o = (half * 4 + n) * 16 + l15;
    float wm = G_W1[o * 257 + 256];
    float b = G_b1[o];
#pragma unroll
    for (int r = 0; r < 4; ++r)
      gh[tg * 16 + l4 * 4 + r][o] = ftanh_acc(fmaf(mf[r], wm, acc[n][r]) + b);
  }
  __syncthreads();

  {                                         // layer 2: thread = (token, expert)
    int t2 = tid >> 3, e2 = tid & 7;
    float lg = 0.f;
    for (int o2 = 0; o2 < 128; ++o2)
      lg = fmaf(gh[t2][o2], G_W2[e2 * 128 + o2], lg);
    float s = (lg + G_b2[e2]) / 0.7f;
    lgs[t2][e2] = fminf(fmaxf(s, -10.f), 10.f);
  }
  __syncthreads();

  if (wv == 0) {                            // 64 tokens on 64 lanes
    int token = tb + lane;
    float v[8];
#pragma unroll
    for (int e = 0; e < 8; ++e) v[e] = lgs[lane][e];
    float tv[5]; int ti[5]; unsigned msk = 0;
    for (int kk = 0; kk < 5; ++kk) {
      float best = -1e30f; int bi = 0;
      for (int e = 0; e < 8; ++e)
        if (!((msk >> e) & 1u) && v[e] > best) { best = v[e]; bi = e; }
      tv[kk] = best; ti[kk] = bi; msk |= 1u << bi;
    }
    float uw[8];
#pragma unroll
    for (int e = 0; e < 8; ++e) uw[e] = 0.f;
    if (tv[3] - tv[4] < DELTA) {            // near-tie -> np-exact recompute later
      int idx = atomicAdd(cnt, 1);
      list[idx] = token;
    } else {
      float mx = tv[0], den = 0.f, wk4[4];
#pragma unroll
      for (int kk = 0; kk < 4; ++kk) { wk4[kk] = expf(tv[kk] - mx); den += wk4[kk]; }
#pragma unroll
      for (int e = 0; e < 8; ++e) {
        float val = 0.f;
#pragma unroll
        for (int kk = 0; kk < 4; ++kk) if (ti[kk] == e) val = wk4[kk] / den;
        w8full[(size_t)token * 8 + e] = val;
      }
      float dall = 0.f, pe[8];
#pragma unroll
      for (int e = 0; e < 8; ++e) { pe[e] = expf(v[e] - mx); dall += pe[e]; }
#pragma unroll
      for (int e = 0; e < 8; ++e) uw[e] = pe[e] / dall;
    }
    for (int m = 1; m <= 32; m <<= 1)
#pragma unroll
      for (int e = 0; e < 8; ++e) uw[e] += __shfl_xor(uw[e], m);
    if (lane == 0)
      for (int e = 0; e < 8; ++e) atomicAdd(usage + e, uw[e]);
  }
}

// ============== gate_slow v3: LDS W1T + 2 tokens/wave (4-chain ILP) ==============
__global__ __launch_bounds__(256) void gate_slow_kernel(
    const float* __restrict__ x, const int* __restrict__ modality,
    const float* __restrict__ W1T, const float* __restrict__ G_b1,
    const float* __restrict__ G_W2, const float* __restrict__ G_b2,
    const int* __restrict__ cnt, const int* __restrict__ list,
    float* __restrict__ w8full, float* __restrict__ usage)
{
  __shared__ float w1l[32896];              // [257][128] f32
  __shared__ float w2l[8][132];
  __shared__ float xs[4][2][256];
  __shared__ float gh[4][2][128];
  const int n = *cnt;
  if (blockIdx.x * 8 >= n) return;          // no tokens for this block

  for (int idx = threadIdx.x; idx < 8224; idx += 256)
    ((float4*)w1l)[idx] = ((const float4*)W1T)[idx];
  for (int idx = threadIdx.x; idx < 1024; idx += 256)
    w2l[idx >> 7][idx & 127] = G_W2[idx];
  __syncthreads();

  const int wvl = threadIdx.x >> 6, lane = threadIdx.x & 63;
  for (int i0 = blockIdx.x * 8 + wvl * 2; i0 < n; i0 += 2048) {
    const bool v1 = (i0 + 1) < n;
    const int T0 = __builtin_amdgcn_readfirstlane(list[i0]);
    const int T1 = __builtin_amdgcn_readfirstlane(v1 ? list[i0 + 1] : list[i0]);
#pragma unroll
    for (int q = 0; q < 4; ++q) {
      xs[wvl][0][q * 64 + lane] = x[(size_t)T0 * 256 + q * 64 + lane];
      xs[wvl][1][q * 64 + lane] = x[(size_t)T1 * 256 + q * 64 + lane];
    }
    float a0 = 0.f, a1 = 0.f, c0 = 0.f, c1 = 0.f;
#pragma unroll 8
    for (int k = 0; k < 256; ++k) {         // exact sequential-k chains (np order)
      float w0 = w1l[k * 128 + lane];
      float w1 = w1l[k * 128 + 64 + lane];
      float x0 = xs[wvl][0][k];
      float x1 = xs[wvl][1][k];
      a0 = fmaf(x0, w0, a0);
      a1 = fmaf(x0, w1, a1);
      c0 = fmaf(x1, w0, c0);
      c1 = fmaf(x1, w1, c1);
    }
    {
      float xm0 = (float)modality[T0];
      float xm1 = (float)modality[T1];
      float w0 = w1l[256 * 128 + lane];
      float w1 = w1l[256 * 128 + 64 + lane];
      a0 = fmaf(xm0, w0, a0);
      a1 = fmaf(xm0, w1, a1);
      c0 = fmaf(xm1, w0, c0);
      c1 = fmaf(xm1, w1, c1);
    }
    gh[wvl][0][lane]      = (float)tanh((double)(a0 + G_b1[lane]));
    gh[wvl][0][64 + lane] = (float)tanh((double)(a1 + G_b1[64 + lane]));
    gh[wvl][1][lane]      = (float)tanh((double)(c0 + G_b1[lane]));
    gh[wvl][1][64 + lane] = (float)tanh((double)(c1 + G_b1[64 + lane]));
    float lg = 0.f;
    if (lane < 16) {
      int tt2 = lane >> 3, ee = lane & 7;
      for (int o = 0; o < 128; ++o)         // exact sequential-o chain
        lg = fmaf(gh[wvl][tt2][o], w2l[ee][o], lg);
    }
    float v[8];
#pragma unroll
    for (int e = 0; e < 8; ++e) v[e] = __shfl(lg, (lane & 8) + e);
    if (lane == 0 || (lane == 8 && v1)) {
      const int T = (lane == 0) ? T0 : T1;
#pragma unroll
      for (int e = 0; e < 8; ++e)
        v[e] = fminf(fmaxf((v[e] + G_b2[e]) / 0.7f, -10.f), 10.f);
      float tv[4]; int ti[4]; unsigned msk = 0;
      for (int kk = 0; kk < 4; ++kk) {
        float best = -1e30f; int bi = 0;
        for (int e = 0; e < 8; ++e)
          if (!((msk >> e) & 1u) && v[e] > best) { best = v[e]; bi = e; }
        tv[kk] = best; ti[kk] = bi; msk |= 1u << bi;
      }
      float mx = tv[0], den = 0.f, wk4[4];
#pragma unroll
      for (int kk = 0; kk < 4; ++kk) { wk4[kk] = expf(tv[kk] - mx); den += wk4[kk]; }
#pragma unroll
      for (int e = 0; e < 8; ++e) {
        float val = 0.f;
#pragma unroll
        for (int kk = 0; kk < 4; ++kk) if (ti[kk] == e) val = wk4[kk] / den;
        w8full[(size_t)T * 8 + e] = val;
      }
      float dall = 0.f, pe[8];
#pragma unroll
      for (int e = 0; e < 8; ++e) { pe[e] = expf(v[e] - mx); dall += pe[e]; }
      for (int e = 0; e < 8; ++e) atomicAdd(usage + e, pe[e] / dall);
    }
  }
}

// ============== moe v11: fam loop + DMA weight staging (no reg prefetch) ==============
__global__ __launch_bounds__(512, 2) void moe_kernel(
    const float* __restrict__ x,
    const unsigned short* __restrict__ W1cat, const unsigned short* __restrict__ W2cat,
    const float* __restrict__ b1cat, const float* __restrict__ b2cat,
    const float* __restrict__ lng, const float* __restrict__ lnb,
    const float* __restrict__ bsc, const float* __restrict__ bbi,
    const float* __restrict__ w8full, float* __restrict__ out)
{
  __shared__ unsigned char smem[131072];    // W1L 64K | W2L 32K | HS 8x4K
  short8* W1L = (short8*)smem;
  short8* W2L = (short8*)(smem + 65536);
  unsigned char* HS = smem + 98304 + (threadIdx.x >> 6) * 4096;

  const int tid = threadIdx.x;
  const int wv = tid >> 6, lane = tid & 63;
  const int l15 = lane & 15, l4 = lane >> 4;
  const int tb = blockIdx.x * 128 + wv * 16;

  short8 A[8];
#pragma unroll
  for (int ks = 0; ks < 8; ++ks) {
    const float* xr = x + (size_t)(tb + l15) * 256 + ks * 32 + l4 * 8;
    float4 u = *(const float4*)xr, v = *(const float4*)(xr + 4);
    short8 a;
    a[0]=(short)f2bf(u.x); a[1]=(short)f2bf(u.y); a[2]=(short)f2bf(u.z); a[3]=(short)f2bf(u.w);
    a[4]=(short)f2bf(v.x); a[5]=(short)f2bf(v.y); a[6]=(short)f2bf(v.z); a[7]=(short)f2bf(v.w);
    A[ks] = a;
  }

  f32x4 zero = {0.f, 0.f, 0.f, 0.f};
  f32x4 pacc[8];
#pragma unroll
  for (int nt = 0; nt < 8; ++nt) pacc[nt] = zero;
  const float RS = 1.0f / sqrtf(1.0f + 1e-5f);

  for (int g = 0; g < 9; ++g) {
    const int type = (g < 2) ? 0 : (g < 4) ? 1 : (g < 6) ? 2 : (g < 8) ? 3 : 4;
    const int g2 = (g < 4) ? g : ((g == 8) ? 6 : g - 2);

    __syncthreads();                        // prev fam's compute done with W1L/W2L
    {                                       // DMA stage: L2 -> LDS, no VGPRs
      const char* W1g = (const char*)W1cat + (size_t)g * 65536;
      const char* W2g = (const char*)W2cat + (size_t)g2 * 32768;
      char* W1Lb = (char*)smem;
      char* W2Lb = (char*)smem + 65536;
      const int wb = wv * 1024;
#pragma unroll
      for (int i = 0; i < 8; ++i) {
        int off = i * 8192 + wb;
        gld_lds16(W1g + off + lane * 16, W1Lb + off);
      }
#pragma unroll
      for (int i = 0; i < 4; ++i) {
        int off = i * 8192 + wb;
        gld_lds16(W2g + off + lane * 16, W2Lb + off);
      }
      asm volatile("s_waitcnt vmcnt(0)" ::: "memory");
    }
    __syncthreads();                        // all waves' DMAs complete

    f32x4 acc[8];
#pragma unroll
    for (int nt = 0; nt < 8; ++nt) acc[nt] = zero;
#pragma unroll
    for (int ks = 0; ks < 8; ++ks)
#pragma unroll
      for (int nt = 0; nt < 8; ++nt)
        acc[nt] = MFMA16(A[ks], W1L[(ks * 8 + nt) * 64 + lane], acc[nt]);

    const float* b1 = b1cat + g * 128;

    if (type == 2) {
#pragma unroll
      for (int r = 0; r < 4; ++r) {
        float wv_ = w8full[(size_t)(tb + l4 * 4 + r) * 8 + g];
#pragma unroll
        for (int nt = 0; nt < 8; ++nt) {
          float h = fgelu(acc[nt][r] + b1[nt * 16 + l15]);
          pacc[nt][r] += wv_ * h;
        }
      }
      continue;
    }
#pragma unroll
    for (int r = 0; r < 4; ++r)
#pragma unroll
      for (int nt = 0; nt < 8; ++nt) {
        float h = acc[nt][r] + b1[nt * 16 + l15];
        if (type == 0)      h = fmaxf(h, 0.f);
        else if (type == 1) {
          int col = (g - 2) * 128 + nt * 16 + l15;
          h = ftanh(h) * RS * bsc[col] + bbi[col];
        }
        else if (type == 3) h = fsilu(h);
        else                h = fmaxf(h, 0.f);
        acc[nt][r] = h;
      }
    if (type >= 3) {
      int li = (type == 4) ? 2 : (g - 6);
#pragma unroll
      for (int r = 0; r < 4; ++r) {
        float s1 = 0.f, s2 = 0.f;
#pragma unroll
        for (int nt = 0; nt < 8; ++nt) { float h = acc[nt][r]; s1 += h; s2 += h * h; }
        for (int m = 1; m <= 8; m <<= 1) { s1 += __shfl_xor(s1, m); s2 += __shfl_xor(s2, m); }
        float mu = s1 * (1.f / 128.f);
        float var = s2 * (1.f / 128.f) - mu * mu;
        float sc = __builtin_amdgcn_rsqf(var + 1e-5f);
#pragma unroll
        for (int nt = 0; nt < 8; ++nt) {
          int col = nt * 16 + l15;
          acc[nt][r] = (acc[nt][r] - mu) * sc * lng[li * 128 + col] + lnb[li * 128 + col];
        }
      }
    }
#pragma unroll
    for (int r = 0; r < 4; ++r) {
      int row = l4 * 4 + r;
#pragma unroll
      for (int nt = 0; nt < 8; ++nt) {
        int bytecol = (nt * 16 + l15) * 2;
        int addr = row * 256 + ((((bytecol >> 4) ^ (row & 7)) << 4) | (bytecol & 15));
        *(unsigned short*)(HS + addr) = f2bf(acc[nt][r]);
      }
    }
    short8 a2[4];
#pragma unroll
    for (int ks = 0; ks < 4; ++ks) {
      int ar = l15 * 256 + ((((ks * 4 + l4) ^ (l15 & 7)) << 4));
      a2[ks] = *(const short8*)(HS + ar);
    }
    f32x4 acc2[8];
#pragma unroll
    for (int nt = 0; nt < 8; ++nt) acc2[nt] = zero;
#pragma unroll
    for (int ks = 0; ks < 4; ++ks)
#pragma unroll
      for (int nt = 0; nt < 8; ++nt)
        acc2[nt] = MFMA16(a2[ks], W2L[(ks * 8 + nt) * 64 + lane], acc2[nt]);

    const float* b2 = b2cat + g2 * 128;
    if (type == 4) {
#pragma unroll
      for (int r = 0; r < 4; ++r) {
        int token = tb + l4 * 4 + r;
#pragma unroll
        for (int nt = 0; nt < 8; ++nt)
          out[(size_t)token * 128 + nt * 16 + l15] = acc2[nt][r] + b2[nt * 16 + l15];
      }
    } else {
#pragma unroll
      for (int r = 0; r < 4; ++r) {
        float wv_ = w8full[(size_t)(tb + l4 * 4 + r) * 8 + g];
#pragma unroll
        for (int nt = 0; nt < 8; ++nt)
          pacc[nt][r] += wv_ * (acc2[nt][r] + b2[nt * 16 + l15]);
      }
    }
  }
#pragma unroll
  for (int r = 0; r < 4; ++r) {
    int token = tb + l4 * 4 + r;
#pragma unroll
    for (int nt = 0; nt < 8; ++nt)
      out[4194304 + (size_t)token * 128 + nt * 16 + l15] = pacc[nt][r];
  }
}

// ============== aux scalar ==============
__global__ void aux_kernel(const float* __restrict__ usage, float* __restrict__ out) {
  if (threadIdx.x == 0 && blockIdx.x == 0) {
    float a = 0.f;
    for (int e = 0; e < 8; ++e) {
      float u = usage[e] * (1.0f / 32768.0f);
      a += 0.125f * (logf(0.125f) - logf(u + 1e-10f));
    }
    out[8388608] = a * 0.125f;
  }
}

extern "C" void kernel_launch(void* const* d_in, const int* in_sizes, int n_in,
                              void* d_out, int out_size, void* d_ws, size_t ws_size,
                              hipStream_t stream) {
  (void)in_sizes; (void)n_in; (void)out_size; (void)ws_size;
  const float* x    = (const float*)d_in[0];
  const int*   mod  = (const int*)d_in[1];
  const float* A_W1 = (const float*)d_in[2];
  const float* A_b1 = (const float*)d_in[3];
  const float* A_W2 = (const float*)d_in[4];
  const float* A_b2 = (const float*)d_in[5];
  const float* B_W1 = (const float*)d_in[6];
  const float* B_b1 = (const float*)d_in[7];
  const float* B_g  = (const float*)d_in[8];
  const float* B_be = (const float*)d_in[9];
  const float* B_W2 = (const float*)d_in[10];
  const float* B_b2 = (const float*)d_in[11];
  const float* C_cw = (const float*)d_in[12];
  const float* C_cb = (const float*)d_in[13];
  const float* C_W  = (const float*)d_in[14];
  const float* C_b  = (const float*)d_in[15];
  const float* D_W1 = (const float*)d_in[16];
  const float* D_b1 = (const float*)d_in[17];
  const float* D_g  = (const float*)d_in[18];
  const float* D_be = (const float*)d_in[19];
  const float* D_W2 = (const float*)d_in[20];
  const float* D_b2 = (const float*)d_in[21];
  const float* S_W1 = (const float*)d_in[22];
  const float* S_b1 = (const float*)d_in[23];
  const float* S_g  = (const float*)d_in[24];
  const float* S_be = (const float*)d_in[25];
  const float* S_W2 = (const float*)d_in[26];
  const float* S_b2 = (const float*)d_in[27];
  const float* G_W1 = (const float*)d_in[28];
  const float* G_b1 = (const float*)d_in[29];
  const float* G_W2 = (const float*)d_in[30];
  const float* G_b2 = (const float*)d_in[31];

  char* ws = (char*)d_ws;
  unsigned short* W1cat = (unsigned short*)(ws + OFF_W1CAT);
  unsigned short* W2cat = (unsigned short*)(ws + OFF_W2CAT);
  float* W1T    = (float*)(ws + OFF_W1T);
  unsigned short* GW1HF = (unsigned short*)(ws + OFF_GW1HF);
  unsigned short* GW1LF = (unsigned short*)(ws + OFF_GW1LF);
  float* b1cat  = (float*)(ws + OFF_B1);
  float* b2cat  = (float*)(ws + OFF_B2);
  float* lng    = (float*)(ws + OFF_LNG);
  float* lnb    = (float*)(ws + OFF_LNB);
  float* bsc    = (float*)(ws + OFF_BSC);
  float* bbi    = (float*)(ws + OFF_BBI);
  float* usage  = (float*)(ws + OFF_USAGE);
  float* w8full = (float*)(ws + OFF_W8);
  int*   cnt    = (int*)(ws + OFF_CNT);
  int*   list   = (int*)(ws + OFF_LIST);
  float* out    = (float*)d_out;

  prep_kernel<<<1870, 256, 0, stream>>>(A_W1, A_b1, A_W2, A_b2, B_W1, B_b1, B_g, B_be,
      B_W2, B_b2, C_cw, C_cb, C_W, C_b, D_W1, D_b1, D_g, D_be, D_W2, D_b2,
      S_W1, S_b1, S_g, S_be, S_W2, S_b2, G_W1,
      W1cat, W2cat, W1T, GW1HF, GW1LF, b1cat, b2cat, lng, lnb, bsc, bbi, usage);
  prep2_kernel<<<4, 256, 0, stream>>>(C_cw, C_cb, C_W, b1cat, cnt);
  gate_fast_kernel<<<512, 512, 0, stream>>>(x, mod, GW1HF, GW1LF, G_W1, G_b1,
      G_W2, G_b2, w8full, usage, cnt, list);
  gate_slow_kernel<<<256, 256, 0, stream>>>(x, mod, W1T, G_b1, G_W2, G_b2,
      cnt, list, w8full, usage);
  moe_kernel<<<256, 512, 0, stream>>>(x, W1cat, W2cat, b1cat, b2cat, lng, lnb,
      bsc, bbi, w8full, out);
  aux_kernel<<<1, 64, 0, stream>>>(usage, out);
}